// Round 7
// baseline (511.317 us; speedup 1.0000x reference)
//
#include <hip/hip_runtime.h>
#include <hip/hip_cooperative_groups.h>

namespace cg = cooperative_groups;

// GCN: out = agg(relu(agg(F)@W1 + b1)) @ W2 + b2
// Reordered (agg linear): P1 = F@W1 (bf16); A1 = b1 + agg(P1); P2 = relu(A1)@W2 (bf16);
//                         out = b2 + agg(P2)
// ONE cooperative kernel, 5 phases separated by grid.sync():
//   A: W1->LDS, zero cnt/gcur
//   B: stage (counting-sort edges into 8 XCD buckets) + gemm1  [independent, overlapped]
//   C: fill2 — group g = bid&7 bins bucket g into padded per-node slots (XCD-local;
//      same block that writes slots aggregates them later -> same-L2 guaranteed)
//   D: agg1 + bias + relu + gemm2 -> P2b
//   E: agg2 + bias -> out
// Rationale: rounds 2-6 showed per-launch fixed cost (launch + ramp + drain) dominates;
// mandatory HBM traffic is only ~18 MB (~3 us).

#define NF 128
#define H1 64
#define H2 32
#define CAP 128       // slot capacity/node; deg ~ Poisson(32), P(>128) ~ 1e-30; guarded
#define CAPSH 7
#define NG8 8         // node-range groups (== XCDs)
#define NTHR 256

__device__ __forceinline__ float blo(unsigned u) { return __uint_as_float(u << 16); }
__device__ __forceinline__ float bhi(unsigned u) { return __uint_as_float(u & 0xffff0000u); }
__device__ __forceinline__ unsigned short f2b(float f) {   // fp32 -> bf16 RNE
    unsigned x = __float_as_uint(f);
    return (unsigned short)((x + 0x7fffu + ((x >> 16) & 1u)) >> 16);
}

__launch_bounds__(NTHR, 4)
__global__ void fused_kernel(const float* __restrict__ F, const float* __restrict__ W1,
                             const float* __restrict__ b1, const float* __restrict__ W2,
                             const float* __restrict__ b2, const int* __restrict__ src,
                             const int* __restrict__ dst, unsigned short* __restrict__ P1b,
                             unsigned short* __restrict__ P2b, unsigned short* __restrict__ slots,
                             int* __restrict__ cnt, unsigned* __restrict__ staged,
                             float* __restrict__ out, int n_nodes, int n_edges,
                             int sz, int capg) {
    cg::grid_group grid = cg::this_grid();
    __shared__ __align__(16) float w[NF * H1];   // 32 KB: W1 in phase B; W2+arow in phase D
    __shared__ int lcnt[NG8], lbase[NG8];
    const int t = threadIdx.x;
    const int bid = blockIdx.x;
    const int nblk = gridDim.x;
    int* gcur = cnt + n_nodes;                   // [8], zeroed with cnt

    // ---------- Phase A: W1 -> LDS; zero cnt+gcur ----------
    {
        const float4* w4 = (const float4*)W1;
        float4* ws4 = (float4*)w;
#pragma unroll
        for (int j = 0; j < (NF * H1 / 4) / NTHR; ++j)
            ws4[t + NTHR * j] = w4[t + NTHR * j];
        for (int i = bid * NTHR + t; i < n_nodes + NG8; i += nblk * NTHR) cnt[i] = 0;
    }
    __threadfence();
    grid.sync();   // also orders LDS (block barrier included)

    // ---------- Phase B: stage edges into buckets, then gemm1 ----------
    for (int e0 = bid * (NTHR * 4); e0 < n_edges; e0 += nblk * (NTHR * 4)) {
        if (t < NG8) lcnt[t] = 0;
        __syncthreads();
        int i4 = e0 + t * 4;
        int dd[4], ss[4], bb[4], pp[4];
        if (i4 + 4 <= n_edges) {
            int4 d4 = *(const int4*)(dst + i4);
            int4 s4 = *(const int4*)(src + i4);
            dd[0] = d4.x; dd[1] = d4.y; dd[2] = d4.z; dd[3] = d4.w;
            ss[0] = s4.x; ss[1] = s4.y; ss[2] = s4.z; ss[3] = s4.w;
        } else {
#pragma unroll
            for (int k = 0; k < 4; ++k) {
                int e = i4 + k;
                dd[k] = (e < n_edges) ? dst[e] : -1;
                ss[k] = (e < n_edges) ? src[e] : 0;
            }
        }
#pragma unroll
        for (int k = 0; k < 4; ++k) {
            if (dd[k] >= 0) {
                bb[k] = (unsigned)dd[k] / (unsigned)sz;
                pp[k] = atomicAdd(&lcnt[bb[k]], 1);
            }
        }
        __syncthreads();
        if (t < NG8) lbase[t] = lcnt[t] ? atomicAdd(&gcur[t], lcnt[t]) : 0;
        __syncthreads();
#pragma unroll
        for (int k = 0; k < 4; ++k) {
            if (dd[k] >= 0) {
                int pos = lbase[bb[k]] + pp[k];
                if (pos < capg)
                    staged[(size_t)bb[k] * capg + pos] = ((unsigned)dd[k] << 16) | (unsigned)ss[k];
            }
        }
        __syncthreads();   // protect lcnt reinit on next trip
    }
    {
        int wid = t >> 6, lane = t & 63;
        for (int r0 = bid * 32; r0 < n_nodes; r0 += nblk * 32) {
#pragma unroll
            for (int r = 0; r < 8; ++r) {
                int row = r0 + wid * 8 + r;
                if (row >= n_nodes) break;
                const float4* f4 = (const float4*)(F + (size_t)row * NF);
                float acc = 0.f;
#pragma unroll 8
                for (int k4 = 0; k4 < NF / 4; ++k4) {
                    float4 fv = f4[k4];
                    acc += fv.x * w[(k4 * 4 + 0) * H1 + lane];
                    acc += fv.y * w[(k4 * 4 + 1) * H1 + lane];
                    acc += fv.z * w[(k4 * 4 + 2) * H1 + lane];
                    acc += fv.w * w[(k4 * 4 + 3) * H1 + lane];
                }
                P1b[(size_t)row * H1 + lane] = f2b(acc);
            }
        }
    }
    __threadfence();
    grid.sync();

    // ---------- Phase C: fill2 — XCD-local slot binning ----------
    {
        int g = bid & (NG8 - 1), gi = bid >> 3;
        int ecnt = min(gcur[g], capg);
        const unsigned* sg = staged + (size_t)g * capg;
        int stride = (nblk >> 3) * NTHR * 4;
        for (int j = (gi * NTHR + t) * 4; j < ecnt; j += stride) {
            if (j + 4 <= ecnt) {
                uint4 u = *(const uint4*)(sg + j);
                int d, p;
                d = u.x >> 16; p = atomicAdd(&cnt[d], 1); if (p < CAP) slots[(d << CAPSH) + p] = (unsigned short)(u.x & 0xffffu);
                d = u.y >> 16; p = atomicAdd(&cnt[d], 1); if (p < CAP) slots[(d << CAPSH) + p] = (unsigned short)(u.y & 0xffffu);
                d = u.z >> 16; p = atomicAdd(&cnt[d], 1); if (p < CAP) slots[(d << CAPSH) + p] = (unsigned short)(u.z & 0xffffu);
                d = u.w >> 16; p = atomicAdd(&cnt[d], 1); if (p < CAP) slots[(d << CAPSH) + p] = (unsigned short)(u.w & 0xffffu);
            } else {
                for (int k = j; k < ecnt; ++k) {
                    unsigned u = sg[k];
                    int d = u >> 16;
                    int p = atomicAdd(&cnt[d], 1);
                    if (p < CAP) slots[(d << CAPSH) + p] = (unsigned short)(u & 0xffffu);
                }
            }
        }
    }
    __threadfence();
    grid.sync();

    // ---------- Phase D: agg1 + bias + relu + gemm2 -> P2b ----------
    {
        float* w2s = w;                 // [64*32]
        float* arow = w + H1 * H2;      // [4*64]
        const float4* w4 = (const float4*)W2;
        float4* d4 = (float4*)w2s;
        for (int j = t; j < H1 * H2 / 4; j += NTHR) d4[j] = w4[j];
        __syncthreads();
        int wid = t >> 6, lane = t & 63;
        int g = bid & (NG8 - 1), gi = bid >> 3;
        int q = lane >> 4, c = lane & 15;
        int half = lane >> 5, c32 = lane & 31;
        const uint2* P1v = (const uint2*)P1b;          // row = 16 uint2 (64 bf16)
        for (int ni0 = gi * 4; ni0 < sz; ni0 += (nblk >> 3) * 4) {
            int ni = ni0 + wid;
            int node = g * sz + ni;
            if (ni < sz && node < n_nodes) {           // wave-uniform guard
                int deg = min(cnt[node], CAP);
                int base = node << CAPSH;
                float a0 = 0.f, a1 = 0.f, a2 = 0.f, a3 = 0.f;
                float c0 = 0.f, c1 = 0.f, c2 = 0.f, c3 = 0.f;
                int i = 0;
                for (; i + 8 <= deg; i += 8) {
                    int sA = slots[base + i + q];
                    int sB = slots[base + i + 4 + q];
                    uint2 uA = P1v[(sA << 4) + c];
                    uint2 uB = P1v[(sB << 4) + c];
                    a0 += blo(uA.x); a1 += bhi(uA.x); a2 += blo(uA.y); a3 += bhi(uA.y);
                    c0 += blo(uB.x); c1 += bhi(uB.x); c2 += blo(uB.y); c3 += bhi(uB.y);
                }
                for (; i + 4 <= deg; i += 4) {
                    int sA = slots[base + i + q];
                    uint2 uA = P1v[(sA << 4) + c];
                    a0 += blo(uA.x); a1 += bhi(uA.x); a2 += blo(uA.y); a3 += bhi(uA.y);
                }
                int r = deg - i;
                if (q < r) {
                    int sA = slots[base + i + q];
                    uint2 uA = P1v[(sA << 4) + c];
                    a0 += blo(uA.x); a1 += bhi(uA.x); a2 += blo(uA.y); a3 += bhi(uA.y);
                }
                a0 += c0; a1 += c1; a2 += c2; a3 += c3;
                a0 += __shfl_xor(a0, 16, 64); a0 += __shfl_xor(a0, 32, 64);
                a1 += __shfl_xor(a1, 16, 64); a1 += __shfl_xor(a1, 32, 64);
                a2 += __shfl_xor(a2, 16, 64); a2 += __shfl_xor(a2, 32, 64);
                a3 += __shfl_xor(a3, 16, 64); a3 += __shfl_xor(a3, 32, 64);
                if (q == 0) {
                    float4 bb = *(const float4*)(b1 + 4 * c);
                    float4 v;
                    v.x = fmaxf(a0 + bb.x, 0.f);
                    v.y = fmaxf(a1 + bb.y, 0.f);
                    v.z = fmaxf(a2 + bb.z, 0.f);
                    v.w = fmaxf(a3 + bb.w, 0.f);
                    *(float4*)&arow[wid * H1 + 4 * c] = v;
                }
                // wave-local LDS bounce (in-order within wave)
                int kb = half * 32;
                float acc2 = 0.f;
#pragma unroll
                for (int k = 0; k < 32; ++k) acc2 += arow[wid * H1 + kb + k] * w2s[(kb + k) * H2 + c32];
                acc2 += __shfl_xor(acc2, 32, 64);
                if (lane < 32) P2b[(size_t)node * H2 + c32] = f2b(acc2);
            }
        }
    }
    __threadfence();
    grid.sync();

    // ---------- Phase E: agg2 + bias -> out ----------
    {
        int wid = t >> 6, lane = t & 63;
        int g = bid & (NG8 - 1), gi = bid >> 3;
        int o = lane >> 3, c = lane & 7;
        const uint2* P2v = (const uint2*)P2b;          // row = 8 uint2 (32 bf16)
        for (int ni0 = gi * 4; ni0 < sz; ni0 += (nblk >> 3) * 4) {
            int ni = ni0 + wid;
            int node = g * sz + ni;
            if (ni < sz && node < n_nodes) {           // wave-uniform guard
                int deg = min(cnt[node], CAP);
                int base = node << CAPSH;
                float a0 = 0.f, a1 = 0.f, a2 = 0.f, a3 = 0.f;
                float c0 = 0.f, c1 = 0.f, c2 = 0.f, c3 = 0.f;
                int i = 0;
                for (; i + 16 <= deg; i += 16) {
                    int sA = slots[base + i + o];
                    int sB = slots[base + i + 8 + o];
                    uint2 uA = P2v[(sA << 3) + c];
                    uint2 uB = P2v[(sB << 3) + c];
                    a0 += blo(uA.x); a1 += bhi(uA.x); a2 += blo(uA.y); a3 += bhi(uA.y);
                    c0 += blo(uB.x); c1 += bhi(uB.x); c2 += blo(uB.y); c3 += bhi(uB.y);
                }
                for (; i + 8 <= deg; i += 8) {
                    int sA = slots[base + i + o];
                    uint2 uA = P2v[(sA << 3) + c];
                    a0 += blo(uA.x); a1 += bhi(uA.x); a2 += blo(uA.y); a3 += bhi(uA.y);
                }
                int r = deg - i;
                if (o < r) {
                    int sA = slots[base + i + o];
                    uint2 uA = P2v[(sA << 3) + c];
                    a0 += blo(uA.x); a1 += bhi(uA.x); a2 += blo(uA.y); a3 += bhi(uA.y);
                }
                a0 += c0; a1 += c1; a2 += c2; a3 += c3;
                a0 += __shfl_xor(a0, 8, 64); a0 += __shfl_xor(a0, 16, 64); a0 += __shfl_xor(a0, 32, 64);
                a1 += __shfl_xor(a1, 8, 64); a1 += __shfl_xor(a1, 16, 64); a1 += __shfl_xor(a1, 32, 64);
                a2 += __shfl_xor(a2, 8, 64); a2 += __shfl_xor(a2, 16, 64); a2 += __shfl_xor(a2, 32, 64);
                a3 += __shfl_xor(a3, 8, 64); a3 += __shfl_xor(a3, 16, 64); a3 += __shfl_xor(a3, 32, 64);
                if (o == 0) {
                    float4 bb = *(const float4*)(b2 + 4 * c);
                    float4 v;
                    v.x = a0 + bb.x; v.y = a1 + bb.y; v.z = a2 + bb.z; v.w = a3 + bb.w;
                    *(float4*)(out + (size_t)node * H2 + 4 * c) = v;
                }
            }
        }
    }
}

// ================= fallback path (round-6 kernels, used only if coop launch fails) ===========
__launch_bounds__(256)
__global__ void gemm1_kernel(const float* __restrict__ F, const float* __restrict__ W1,
                             unsigned short* __restrict__ P1b, int* __restrict__ cntz,
                             int n_zero, int n_nodes) {
    int idx = blockIdx.x * 256 + threadIdx.x;
    if (idx < n_zero) cntz[idx] = 0;
    __shared__ float w[NF][H1];
    const float4* w4 = (const float4*)W1;
    float4* ws4 = (float4*)&w[0][0];
#pragma unroll
    for (int j = 0; j < 8; ++j) ws4[threadIdx.x + 256 * j] = w4[threadIdx.x + 256 * j];
    __syncthreads();
    int wid = threadIdx.x >> 6, lane = threadIdx.x & 63;
#pragma unroll
    for (int r = 0; r < 8; ++r) {
        int row = blockIdx.x * 32 + wid * 8 + r;
        if (row >= n_nodes) break;
        const float4* f4 = (const float4*)(F + (size_t)row * NF);
        float acc = 0.f;
#pragma unroll 8
        for (int k4 = 0; k4 < NF / 4; ++k4) {
            float4 fv = f4[k4];
            acc += fv.x * w[k4 * 4 + 0][lane];
            acc += fv.y * w[k4 * 4 + 1][lane];
            acc += fv.z * w[k4 * 4 + 2][lane];
            acc += fv.w * w[k4 * 4 + 3][lane];
        }
        P1b[(size_t)row * H1 + lane] = f2b(acc);
    }
}

__launch_bounds__(256)
__global__ void stage_kernel(const int* __restrict__ src, const int* __restrict__ dst,
                             unsigned* __restrict__ staged, int* __restrict__ gcur,
                             int n_edges, int sz, int capg) {
    __shared__ int lcnt[NG8];
    __shared__ int lbase[NG8];
    int t = threadIdx.x;
    if (t < NG8) lcnt[t] = 0;
    __syncthreads();
    int i4 = (blockIdx.x * 256 + t) * 4;
    int dd[4], ss[4], bb[4], pp[4];
    if (i4 + 4 <= n_edges) {
        int4 d4 = *(const int4*)(dst + i4);
        int4 s4 = *(const int4*)(src + i4);
        dd[0] = d4.x; dd[1] = d4.y; dd[2] = d4.z; dd[3] = d4.w;
        ss[0] = s4.x; ss[1] = s4.y; ss[2] = s4.z; ss[3] = s4.w;
    } else {
#pragma unroll
        for (int k = 0; k < 4; ++k) {
            int e = i4 + k;
            dd[k] = (e < n_edges) ? dst[e] : -1;
            ss[k] = (e < n_edges) ? src[e] : 0;
        }
    }
#pragma unroll
    for (int k = 0; k < 4; ++k) {
        if (dd[k] >= 0) {
            bb[k] = (unsigned)dd[k] / (unsigned)sz;
            pp[k] = atomicAdd(&lcnt[bb[k]], 1);
        }
    }
    __syncthreads();
    if (t < NG8) lbase[t] = lcnt[t] ? atomicAdd(&gcur[t], lcnt[t]) : 0;
    __syncthreads();
#pragma unroll
    for (int k = 0; k < 4; ++k) {
        if (dd[k] >= 0) {
            int pos = lbase[bb[k]] + pp[k];
            if (pos < capg)
                staged[(size_t)bb[k] * capg + pos] = ((unsigned)dd[k] << 16) | (unsigned)ss[k];
        }
    }
}

#define FILL_BPG 80
__launch_bounds__(256)
__global__ void fill2_kernel(const unsigned* __restrict__ staged, const int* __restrict__ gcur,
                             int* __restrict__ cnt, unsigned short* __restrict__ slots,
                             int capg) {
    int g = blockIdx.x & (NG8 - 1), gi = blockIdx.x >> 3;
    int ecnt = min(gcur[g], capg);
    const unsigned* sg = staged + (size_t)g * capg;
    int stride = FILL_BPG * 256 * 4;
    for (int j = (gi * 256 + threadIdx.x) * 4; j < ecnt; j += stride) {
        if (j + 4 <= ecnt) {
            uint4 u = *(const uint4*)(sg + j);
            int d, p;
            d = u.x >> 16; p = atomicAdd(&cnt[d], 1); if (p < CAP) slots[(d << CAPSH) + p] = (unsigned short)(u.x & 0xffffu);
            d = u.y >> 16; p = atomicAdd(&cnt[d], 1); if (p < CAP) slots[(d << CAPSH) + p] = (unsigned short)(u.y & 0xffffu);
            d = u.z >> 16; p = atomicAdd(&cnt[d], 1); if (p < CAP) slots[(d << CAPSH) + p] = (unsigned short)(u.z & 0xffffu);
            d = u.w >> 16; p = atomicAdd(&cnt[d], 1); if (p < CAP) slots[(d << CAPSH) + p] = (unsigned short)(u.w & 0xffffu);
        } else {
            for (int k = j; k < ecnt; ++k) {
                unsigned u = sg[k];
                int d = u >> 16;
                int p = atomicAdd(&cnt[d], 1);
                if (p < CAP) slots[(d << CAPSH) + p] = (unsigned short)(u & 0xffffu);
            }
        }
    }
}

__launch_bounds__(256)
__global__ void agg1gemm2_kernel(const unsigned short* __restrict__ P1b,
                                 const int* __restrict__ cnt, const unsigned short* __restrict__ slots,
                                 const float* __restrict__ b1, const float* __restrict__ W2,
                                 unsigned short* __restrict__ P2b, int n_nodes, int sz) {
    __shared__ float w[H1][H2];
    __shared__ float arow[4][H1];
    const float4* w4 = (const float4*)W2;
    float4* ws4 = (float4*)&w[0][0];
#pragma unroll
    for (int j = 0; j < 2; ++j) ws4[threadIdx.x + 256 * j] = w4[threadIdx.x + 256 * j];
    __syncthreads();
    int wid = threadIdx.x >> 6, lane = threadIdx.x & 63;
    int g = blockIdx.x & (NG8 - 1), gi = blockIdx.x >> 3;
    int ni = gi * 4 + wid;
    if (ni >= sz) return;
    int node = g * sz + ni;
    if (node >= n_nodes) return;
    int deg = min(cnt[node], CAP);
    int base = node << CAPSH;
    int q = lane >> 4, c = lane & 15;
    const uint2* P1v = (const uint2*)P1b;
    float a0 = 0.f, a1 = 0.f, a2 = 0.f, a3 = 0.f;
    float c0 = 0.f, c1 = 0.f, c2 = 0.f, c3 = 0.f;
    int i = 0;
    for (; i + 8 <= deg; i += 8) {
        int sA = slots[base + i + q];
        int sB = slots[base + i + 4 + q];
        uint2 uA = P1v[(sA << 4) + c];
        uint2 uB = P1v[(sB << 4) + c];
        a0 += blo(uA.x); a1 += bhi(uA.x); a2 += blo(uA.y); a3 += bhi(uA.y);
        c0 += blo(uB.x); c1 += bhi(uB.x); c2 += blo(uB.y); c3 += bhi(uB.y);
    }
    for (; i + 4 <= deg; i += 4) {
        int sA = slots[base + i + q];
        uint2 uA = P1v[(sA << 4) + c];
        a0 += blo(uA.x); a1 += bhi(uA.x); a2 += blo(uA.y); a3 += bhi(uA.y);
    }
    int r = deg - i;
    if (q < r) {
        int sA = slots[base + i + q];
        uint2 uA = P1v[(sA << 4) + c];
        a0 += blo(uA.x); a1 += bhi(uA.x); a2 += blo(uA.y); a3 += bhi(uA.y);
    }
    a0 += c0; a1 += c1; a2 += c2; a3 += c3;
    a0 += __shfl_xor(a0, 16, 64); a0 += __shfl_xor(a0, 32, 64);
    a1 += __shfl_xor(a1, 16, 64); a1 += __shfl_xor(a1, 32, 64);
    a2 += __shfl_xor(a2, 16, 64); a2 += __shfl_xor(a2, 32, 64);
    a3 += __shfl_xor(a3, 16, 64); a3 += __shfl_xor(a3, 32, 64);
    if (q == 0) {
        float4 bb = *(const float4*)(b1 + 4 * c);
        float4 v;
        v.x = fmaxf(a0 + bb.x, 0.f);
        v.y = fmaxf(a1 + bb.y, 0.f);
        v.z = fmaxf(a2 + bb.z, 0.f);
        v.w = fmaxf(a3 + bb.w, 0.f);
        *(float4*)&arow[wid][4 * c] = v;
    }
    int half = lane >> 5, c32 = lane & 31;
    int kb = half * 32;
    float acc2 = 0.f;
#pragma unroll
    for (int k = 0; k < 32; ++k) acc2 += arow[wid][kb + k] * w[kb + k][c32];
    acc2 += __shfl_xor(acc2, 32, 64);
    if (lane < 32) P2b[(size_t)node * H2 + c32] = f2b(acc2);
}

__launch_bounds__(256)
__global__ void agg2_kernel(const unsigned short* __restrict__ P2b,
                            const int* __restrict__ cnt, const unsigned short* __restrict__ slots,
                            const float* __restrict__ b2, float* __restrict__ out,
                            int n_nodes, int sz) {
    int wid = threadIdx.x >> 6, lane = threadIdx.x & 63;
    int g = blockIdx.x & (NG8 - 1), gi = blockIdx.x >> 3;
    int ni = gi * 4 + wid;
    if (ni >= sz) return;
    int node = g * sz + ni;
    if (node >= n_nodes) return;
    int deg = min(cnt[node], CAP);
    int base = node << CAPSH;
    int o = lane >> 3, c = lane & 7;
    const uint2* P2v = (const uint2*)P2b;
    float a0 = 0.f, a1 = 0.f, a2 = 0.f, a3 = 0.f;
    float c0 = 0.f, c1 = 0.f, c2 = 0.f, c3 = 0.f;
    int i = 0;
    for (; i + 16 <= deg; i += 16) {
        int sA = slots[base + i + o];
        int sB = slots[base + i + 8 + o];
        uint2 uA = P2v[(sA << 3) + c];
        uint2 uB = P2v[(sB << 3) + c];
        a0 += blo(uA.x); a1 += bhi(uA.x); a2 += blo(uA.y); a3 += bhi(uA.y);
        c0 += blo(uB.x); c1 += bhi(uB.x); c2 += blo(uB.y); c3 += bhi(uB.y);
    }
    for (; i + 8 <= deg; i += 8) {
        int sA = slots[base + i + o];
        uint2 uA = P2v[(sA << 3) + c];
        a0 += blo(uA.x); a1 += bhi(uA.x); a2 += blo(uA.y); a3 += bhi(uA.y);
    }
    int r = deg - i;
    if (o < r) {
        int sA = slots[base + i + o];
        uint2 uA = P2v[(sA << 3) + c];
        a0 += blo(uA.x); a1 += bhi(uA.x); a2 += blo(uA.y); a3 += bhi(uA.y);
    }
    a0 += c0; a1 += c1; a2 += c2; a3 += c3;
    a0 += __shfl_xor(a0, 8, 64); a0 += __shfl_xor(a0, 16, 64); a0 += __shfl_xor(a0, 32, 64);
    a1 += __shfl_xor(a1, 8, 64); a1 += __shfl_xor(a1, 16, 64); a1 += __shfl_xor(a1, 32, 64);
    a2 += __shfl_xor(a2, 8, 64); a2 += __shfl_xor(a2, 16, 64); a2 += __shfl_xor(a2, 32, 64);
    a3 += __shfl_xor(a3, 8, 64); a3 += __shfl_xor(a3, 16, 64); a3 += __shfl_xor(a3, 32, 64);
    if (o == 0) {
        float4 bb = *(const float4*)(b2 + 4 * c);
        float4 v;
        v.x = a0 + bb.x; v.y = a1 + bb.y; v.z = a2 + bb.z; v.w = a3 + bb.w;
        *(float4*)(out + (size_t)node * H2 + 4 * c) = v;
    }
}

extern "C" void kernel_launch(void* const* d_in, const int* in_sizes, int n_in,
                              void* d_out, int out_size, void* d_ws, size_t ws_size,
                              hipStream_t stream) {
    const float* F  = (const float*)d_in[0];
    const float* W1 = (const float*)d_in[1];
    const float* b1 = (const float*)d_in[2];
    const float* W2 = (const float*)d_in[3];
    const float* b2 = (const float*)d_in[4];
    const int* src  = (const int*)d_in[5];
    const int* dst  = (const int*)d_in[6];
    float* out = (float*)d_out;

    int n_nodes = in_sizes[0] / NF;   // 20000
    int n_edges = in_sizes[5];        // 640000
    int sz = (n_nodes + NG8 - 1) / NG8;               // nodes per group (2500)
    int capg = n_edges / NG8 + 8192;                  // staged bucket capacity

    // Workspace layout (~11.9 MB):
    unsigned short* P1b = (unsigned short*)d_ws;              // [n][64] bf16
    unsigned short* P2b = P1b + (size_t)n_nodes * H1;         // [n][32] bf16
    unsigned short* slots = P2b + (size_t)n_nodes * H2;       // [n][CAP] ushort
    int* cnt = (int*)(slots + ((size_t)n_nodes << CAPSH));    // [n] + gcur[8] appended
    int* gcur = cnt + n_nodes;
    unsigned* staged = (unsigned*)(gcur + NG8);               // [8][capg]

    // Cooperative grid sizing: co-resident by occupancy query (deterministic per device).
    int dev = 0;
    hipGetDevice(&dev);
    int ncu = 256;
    hipDeviceGetAttribute(&ncu, hipDeviceAttributeMultiprocessorCount, dev);
    int maxBpc = 0;
    hipOccupancyMaxActiveBlocksPerMultiprocessor(&maxBpc, (const void*)fused_kernel, NTHR, 0);
    int nblk = maxBpc * ncu;
    if (nblk > 1024) nblk = 1024;
    nblk &= ~7;                       // multiple of 8 for the XCD-group partition
    if (nblk < 8) nblk = 8;

    void* args[] = { (void*)&F, (void*)&W1, (void*)&b1, (void*)&W2, (void*)&b2,
                     (void*)&src, (void*)&dst, (void*)&P1b, (void*)&P2b, (void*)&slots,
                     (void*)&cnt, (void*)&staged, (void*)&out,
                     (void*)&n_nodes, (void*)&n_edges, (void*)&sz, (void*)&capg };
    hipError_t err = hipLaunchCooperativeKernel((const void*)fused_kernel, dim3(nblk), dim3(NTHR),
                                                args, 0, stream);
    if (err != hipSuccess) {
        // Fallback: round-6 5-kernel path (identical math).
        gemm1_kernel<<<(n_nodes + 31) / 32, 256, 0, stream>>>(F, W1, P1b, cnt,
                                                              n_nodes + NG8, n_nodes);
        stage_kernel<<<(n_edges + 1023) / 1024, 256, 0, stream>>>(src, dst, staged, gcur,
                                                                  n_edges, sz, capg);
        fill2_kernel<<<FILL_BPG * NG8, 256, 0, stream>>>(staged, gcur, cnt, slots, capg);
        int bpg = (sz + 3) / 4;
        agg1gemm2_kernel<<<bpg * NG8, 256, 0, stream>>>(P1b, cnt, slots, b1, W2, P2b, n_nodes, sz);
        agg2_kernel<<<bpg * NG8, 256, 0, stream>>>(P2b, cnt, slots, b2, out, n_nodes, sz);
    }
}

// Round 8
// 475.038 us; speedup vs baseline: 1.0764x; 1.0764x over previous
//
#include <hip/hip_runtime.h>

// GCN: out = agg(relu(agg(F)@W1 + b1)) @ W2 + b2
// Reordered (agg linear): P1 = F@W1 (bf16); A1 = b1 + agg(P1); P2 = relu(A1)@W2 (bf16);
//                         out = b2 + agg(P2)
// 3 kernels, NO global atomics, NO slot arrays:
//  K1: per-block LDS counting-sort of 2048-edge chunks by coarse bucket (dst>>8, 79
//      buckets) -> coalesced full-line staged runs + per-block bucket offsets; + gemm1.
//  K2: block = 32-node window (625): compact my edges from my bucket's segments into
//      LDS, gather P1b rows, accumulate into LDS fp32 accum via ds_add_f32, relu+gemm2
//      -> P2b. Persists compacted edge list (ebuf) for K3.
//  K3: block = window: gather P2b rows by saved list, LDS-accumulate, +b2 -> out.
// (Round 7 lesson: cooperative grid.sync costs ~200us/sync at 1024 blocks — kernel
//  boundaries are the cheap grid barrier. Round 4 lesson: scattered 4B global stores
//  write-amplify 15x — hence block-contiguous staged runs + LDS-only scatter.)

#define NF 128
#define H1 64
#define H2 32
#define NBK 79        // coarse buckets of 256 nodes (bucket = dst>>8)
#define ECHUNK 2048   // edges per K1 block (512 thr x 4)
#define LEC_CAP 2048  // per-window compacted-edge capacity (mean 1024, +32 sigma; guarded)

__device__ __forceinline__ float blo(unsigned u){ return __uint_as_float(u << 16); }
__device__ __forceinline__ float bhi(unsigned u){ return __uint_as_float(u & 0xffff0000u); }
__device__ __forceinline__ unsigned short f2b(float f){   // fp32 -> bf16 RNE
    unsigned x = __float_as_uint(f);
    return (unsigned short)((x + 0x7fffu + ((x >> 16) & 1u)) >> 16);
}

// ---- K1: counting-sort chunk by coarse bucket (coalesced staged runs) + gemm1 ----
__launch_bounds__(512)
__global__ void k1_kernel(const float* __restrict__ F, const float* __restrict__ W1,
                          const int* __restrict__ src, const int* __restrict__ dst,
                          unsigned* __restrict__ staged, int* __restrict__ bofs,
                          unsigned short* __restrict__ P1b,
                          int n_nodes, int n_edges, int nblk_s) {
    __shared__ __align__(16) float w[NF * H1];   // 32 KB: sort buffer now, W1 later
    __shared__ int lcnt[NBK + 1];
    unsigned* sorted = (unsigned*)w;             // 2048 uints = 8 KB
    const int t = threadIdx.x;
    const int bid = blockIdx.x;

    int e0 = bid * ECHUNK;
    if (e0 < n_edges) {                          // block-uniform guard
        int cnt = min(n_edges - e0, ECHUNK);
        for (int i = t; i < NBK + 1; i += 512) lcnt[i] = 0;
        __syncthreads();
        int i4 = e0 + t * 4;
        int dd[4], ss[4], bb[4], pp[4];
        if (i4 + 4 <= n_edges) {
            int4 d4 = *(const int4*)(dst + i4);
            int4 s4 = *(const int4*)(src + i4);
            dd[0]=d4.x; dd[1]=d4.y; dd[2]=d4.z; dd[3]=d4.w;
            ss[0]=s4.x; ss[1]=s4.y; ss[2]=s4.z; ss[3]=s4.w;
        } else {
#pragma unroll
            for (int k = 0; k < 4; ++k) {
                int e = i4 + k;
                dd[k] = (e < n_edges) ? dst[e] : -1;
                ss[k] = (e < n_edges) ? src[e] : 0;
            }
        }
#pragma unroll
        for (int k = 0; k < 4; ++k)
            if (dd[k] >= 0) { bb[k] = dd[k] >> 8; pp[k] = atomicAdd(&lcnt[bb[k]], 1); }
        __syncthreads();
        if (t == 0) {                            // serial exclusive scan over 80 entries
            int run = 0;
            for (int i = 0; i < NBK + 1; ++i) { int c = lcnt[i]; lcnt[i] = run; run += c; }
        }
        __syncthreads();
#pragma unroll
        for (int k = 0; k < 4; ++k)
            if (dd[k] >= 0) sorted[lcnt[bb[k]] + pp[k]] = ((unsigned)dd[k] << 16) | (unsigned)ss[k];
        __syncthreads();
        for (int j = t; j < cnt; j += 512) staged[(size_t)bid * ECHUNK + j] = sorted[j];
        for (int i = t; i < NBK + 1; i += 512) bofs[i * nblk_s + bid] = lcnt[i];
        __syncthreads();                         // sorted no longer needed; w reused for W1
    }

    // ---- gemm1: P1b[row][64] = F[row][128] @ W1 ----
    {
        const float4* w4 = (const float4*)W1;
        float4* ws4 = (float4*)w;
#pragma unroll
        for (int j = 0; j < 4; ++j) ws4[t + 512 * j] = w4[t + 512 * j];
    }
    __syncthreads();
    int wid = t >> 6, lane = t & 63;
    int row0 = bid * 64 + wid * 8;
#pragma unroll
    for (int r = 0; r < 8; ++r) {
        int row = row0 + r;
        if (row >= n_nodes) break;
        const float4* f4 = (const float4*)(F + (size_t)row * NF);
        float acc = 0.f;
#pragma unroll 8
        for (int k4 = 0; k4 < NF / 4; ++k4) {
            float4 fv = f4[k4];
            acc += fv.x * w[(k4 * 4 + 0) * H1 + lane];
            acc += fv.y * w[(k4 * 4 + 1) * H1 + lane];
            acc += fv.z * w[(k4 * 4 + 2) * H1 + lane];
            acc += fv.w * w[(k4 * 4 + 3) * H1 + lane];
        }
        P1b[(size_t)row * H1 + lane] = f2b(acc);
    }
}

// ---- K2: window agg1 (LDS fp32 accumulate) + relu + gemm2 -> P2b; saves edge list ----
__launch_bounds__(512)
__global__ void k2_kernel(const unsigned short* __restrict__ P1b,
                          const unsigned* __restrict__ staged, const int* __restrict__ bofs,
                          const float* __restrict__ b1, const float* __restrict__ W2,
                          unsigned short* __restrict__ P2b, unsigned* __restrict__ ebuf,
                          int* __restrict__ ecnt2, int nblk_s) {
    __shared__ float accum[32 * H1];             // 8 KB: A1 rows for my 32 nodes
    __shared__ float w2s[H1 * H2];               // 8 KB
    __shared__ unsigned ledge[LEC_CAP];          // 8 KB
    __shared__ int lec;
    const int t = threadIdx.x;
    const int bid = blockIdx.x;                  // window id: nodes [bid*32, bid*32+32)
    const int wid = t >> 6, lane = t & 63;

    {   // init accum = b1 broadcast; W2 -> LDS
        float bv = b1[t & 63];
        accum[t] = bv; accum[t + 512] = bv; accum[t + 1024] = bv; accum[t + 1536] = bv;
        const float4* w4 = (const float4*)W2;
        ((float4*)w2s)[t] = w4[t];
        if (t == 0) lec = 0;
    }
    __syncthreads();

    // compact: pull my window's edges out of my bucket's per-source-block segments
    int bk = bid >> 3;                           // coarse bucket containing this window
    for (int sb = wid; sb < nblk_s; sb += 8) {
        int st = bofs[bk * nblk_s + sb];
        int en = bofs[(bk + 1) * nblk_s + sb];
        const unsigned* seg = staged + (size_t)sb * ECHUNK;
        for (int j = st + lane; j < en; j += 64) {
            unsigned pk = seg[j];
            if ((int)(pk >> 21) == bid) {        // node>>5 == my window
                int p = atomicAdd(&lec, 1);
                if (p < LEC_CAP) ledge[p] = pk;
            }
        }
    }
    __syncthreads();
    int ec = min(lec, LEC_CAP);
    for (int j = t; j < ec; j += 512) ebuf[(size_t)bid * LEC_CAP + j] = ledge[j];
    if (t == 0) ecnt2[bid] = ec;

    // gather-accumulate: half-wave per edge (32 lanes x uint = 128 B row), 2-deep
    {
        int half = lane >> 5, c = lane & 31;
        const unsigned* P1u = (const unsigned*)P1b;
        for (int e = wid * 2 + half; e < ec; e += 32) {
            unsigned pk0 = ledge[e];
            int e1 = e + 16;
            unsigned u0 = P1u[((pk0 & 0xffffu) << 5) + c];
            float* a0p = &accum[((pk0 >> 16) & 31) * H1 + 2 * c];
            if (e1 < ec) {
                unsigned pk1 = ledge[e1];
                unsigned u1 = P1u[((pk1 & 0xffffu) << 5) + c];
                atomicAdd(a0p, blo(u0)); atomicAdd(a0p + 1, bhi(u0));
                float* a1p = &accum[((pk1 >> 16) & 31) * H1 + 2 * c];
                atomicAdd(a1p, blo(u1)); atomicAdd(a1p + 1, bhi(u1));
            } else {
                atomicAdd(a0p, blo(u0)); atomicAdd(a0p + 1, bhi(u0));
            }
        }
    }
    __syncthreads();

    // relu + gemm2: 8 waves x 4 nodes; half-wave k-split + shfl_xor(32)
    {
        int half = lane >> 5, c32 = lane & 31, kb = half * 32;
#pragma unroll
        for (int r = 0; r < 4; ++r) {
            int ni = wid * 4 + r;
            float acc2 = 0.f;
#pragma unroll
            for (int k = 0; k < 32; ++k)
                acc2 += fmaxf(accum[ni * H1 + kb + k], 0.f) * w2s[(kb + k) * H2 + c32];
            acc2 += __shfl_xor(acc2, 32, 64);
            if (half == 0) P2b[(size_t)(bid * 32 + ni) * H2 + c32] = f2b(acc2);
        }
    }
}

// ---- K3: window agg2 (LDS fp32 accumulate) + b2 -> out ----
__launch_bounds__(512)
__global__ void k3_kernel(const unsigned short* __restrict__ P2b,
                          const unsigned* __restrict__ ebuf, const int* __restrict__ ecnt2,
                          const float* __restrict__ b2, float* __restrict__ out) {
    __shared__ float accum2[32 * H2];            // 4 KB
    const int t = threadIdx.x;
    const int bid = blockIdx.x;
    const int wid = t >> 6, lane = t & 63;
    {
        float bv = b2[t & 31];
        accum2[t] = bv; accum2[t + 512] = bv;
    }
    __syncthreads();
    int ec = ecnt2[bid];
    const unsigned* eb = ebuf + (size_t)bid * LEC_CAP;
    {
        int q = lane >> 4, c = lane & 15;        // quarter-wave per edge (16 x uint = 64 B row)
        const unsigned* P2u = (const unsigned*)P2b;
        for (int e = wid * 4 + q; e < ec; e += 64) {
            unsigned pk0 = eb[e];
            int e1 = e + 32;
            unsigned u0 = P2u[((pk0 & 0xffffu) << 4) + c];
            float* a0p = &accum2[((pk0 >> 16) & 31) * H2 + 2 * c];
            if (e1 < ec) {
                unsigned pk1 = eb[e1];
                unsigned u1 = P2u[((pk1 & 0xffffu) << 4) + c];
                atomicAdd(a0p, blo(u0)); atomicAdd(a0p + 1, bhi(u0));
                float* a1p = &accum2[((pk1 >> 16) & 31) * H2 + 2 * c];
                atomicAdd(a1p, blo(u1)); atomicAdd(a1p + 1, bhi(u1));
            } else {
                atomicAdd(a0p, blo(u0)); atomicAdd(a0p + 1, bhi(u0));
            }
        }
    }
    __syncthreads();
    int ni = t >> 4, c16 = t & 15;
    float2 v;
    v.x = accum2[ni * H2 + 2 * c16];
    v.y = accum2[ni * H2 + 2 * c16 + 1];
    *(float2*)(out + (size_t)(bid * 32 + ni) * H2 + 2 * c16) = v;
}

extern "C" void kernel_launch(void* const* d_in, const int* in_sizes, int n_in,
                              void* d_out, int out_size, void* d_ws, size_t ws_size,
                              hipStream_t stream) {
    const float* F  = (const float*)d_in[0];
    const float* W1 = (const float*)d_in[1];
    const float* b1 = (const float*)d_in[2];
    const float* W2 = (const float*)d_in[3];
    const float* b2 = (const float*)d_in[4];
    const int* src  = (const int*)d_in[5];
    const int* dst  = (const int*)d_in[6];
    float* out = (float*)d_out;

    int n_nodes = in_sizes[0] / NF;                       // 20000
    int n_edges = in_sizes[5];                            // 640000
    int nblk_s = (n_edges + ECHUNK - 1) / ECHUNK;         // 313
    int nwin = (n_nodes + 31) / 32;                       // 625 windows

    // Workspace layout (~11.6 MB):
    unsigned short* P1b = (unsigned short*)d_ws;              // [n][64] bf16   2.56 MB
    unsigned short* P2b = P1b + (size_t)n_nodes * H1;         // [n][32] bf16   1.28 MB
    unsigned* staged = (unsigned*)(P2b + (size_t)n_nodes * H2); // [nblk_s][2048] 2.56 MB
    int* bofs = (int*)(staged + (size_t)nblk_s * ECHUNK);     // [NBK+1][nblk_s] 100 KB
    unsigned* ebuf = (unsigned*)(bofs + (size_t)(NBK + 1) * nblk_s); // [nwin][2048] 5.12 MB
    int* ecnt2 = (int*)(ebuf + (size_t)nwin * LEC_CAP);       // [nwin]

    int g1 = nblk_s > (n_nodes + 63) / 64 ? nblk_s : (n_nodes + 63) / 64;   // 313
    k1_kernel<<<g1, 512, 0, stream>>>(F, W1, src, dst, staged, bofs, P1b,
                                      n_nodes, n_edges, nblk_s);
    k2_kernel<<<nwin, 512, 0, stream>>>(P1b, staged, bofs, b1, W2, P2b, ebuf, ecnt2, nblk_s);
    k3_kernel<<<nwin, 512, 0, stream>>>(P2b, ebuf, ecnt2, b2, out);
}

// Round 9
// 96.881 us; speedup vs baseline: 5.2778x; 4.9033x over previous
//
#include <hip/hip_runtime.h>

// GCN: out = agg(relu(agg(F)@W1 + b1)) @ W2 + b2
// Reordered (agg linear): P1 = F@W1 (bf16); A1 = b1 + agg(P1); P2 = relu(A1)@W2 (bf16);
//                         out = b2 + agg(P2)
// Round-6 skeleton (best: 97.3us) + fixes:
//  K1 (two block roles, merged):
//    - stage blocks: LDS counting-sort of a 1024-edge chunk into 8 XCD-group buckets,
//      written as block-local sorted runs + bofs offsets (NO global cursors -> nothing
//      to pre-zero; round-8's k1 pattern, which worked).
//    - gemm1 blocks: P1b = F@W1 (W1 in LDS) + zero cnt.
//  K2 fill2: group g = bid&7 walks its bucket's per-chunk segments -> slot binning
//      (global atomics, XCD-local lines).
//  K3 agg1+relu+gemm2, K4 agg2: gather loops rewritten with FOUR independent
//      slot->row load chains per wave (latency-bound fix; round-8 showed these
//      kernels compile to 16 VGPRs with no pipelining).
// Lessons kept: no grid.sync (r7: ~200us/sync); no per-block compaction scans (r8:
// 300us latency serialization); no rocclr fills (~40us each); XCD-local slot writes
// (r4: 59B HBM per 4B payload without it).

#define NF 128
#define H1 64
#define H2 32
#define CAP 128       // slot capacity/node; deg ~ Poisson(32), P(>128) ~ 1e-30; guarded
#define CAPSH 7
#define NG8 8         // node-range groups (== XCDs)
#define SCHUNK 1024   // edges per stage block
#define FILL_BPG 80   // fill2 blocks per group

__device__ __forceinline__ float blo(unsigned u){ return __uint_as_float(u << 16); }
__device__ __forceinline__ float bhi(unsigned u){ return __uint_as_float(u & 0xffff0000u); }
__device__ __forceinline__ unsigned short f2b(float f){   // fp32 -> bf16 RNE
    unsigned x = __float_as_uint(f);
    return (unsigned short)((x + 0x7fffu + ((x >> 16) & 1u)) >> 16);
}

// ---- K1: stage blocks (bid < nsb) + gemm1 blocks (bid >= nsb) ----
__launch_bounds__(256)
__global__ void k1_kernel(const float* __restrict__ F, const float* __restrict__ W1,
                          const int* __restrict__ src, const int* __restrict__ dst,
                          unsigned* __restrict__ staged, int* __restrict__ bofs,
                          unsigned short* __restrict__ P1b, int* __restrict__ cnt,
                          unsigned inv_sz, int n_nodes, int n_edges, int nsb) {
    __shared__ __align__(16) float w[NF * H1];   // 32 KB (sort buf for stage role)
    __shared__ int lcnt[NG8 + 1];
    const int t = threadIdx.x;
    const int bid = blockIdx.x;

    if (bid < nsb) {
        // ---------- stage role: sort my 1024-edge chunk by group bucket ----------
        unsigned* sorted = (unsigned*)w;         // 1024 uints
        int e0 = bid * SCHUNK;
        int ce = min(n_edges - e0, SCHUNK);
        if (t < NG8 + 1) lcnt[t] = 0;
        __syncthreads();
        int i4 = e0 + t * 4;
        int dd[4], ss[4], bb[4], pp[4];
        if (i4 + 4 <= n_edges) {
            int4 d4 = *(const int4*)(dst + i4);
            int4 s4 = *(const int4*)(src + i4);
            dd[0]=d4.x; dd[1]=d4.y; dd[2]=d4.z; dd[3]=d4.w;
            ss[0]=s4.x; ss[1]=s4.y; ss[2]=s4.z; ss[3]=s4.w;
        } else {
#pragma unroll
            for (int k = 0; k < 4; ++k) {
                int e = i4 + k;
                dd[k] = (e < n_edges) ? dst[e] : -1;
                ss[k] = (e < n_edges) ? src[e] : 0;
            }
        }
#pragma unroll
        for (int k = 0; k < 4; ++k) {
            if (dd[k] >= 0) {
                bb[k] = (int)(unsigned)(((unsigned long long)(unsigned)dd[k] * inv_sz) >> 32);
                pp[k] = atomicAdd(&lcnt[bb[k]], 1);
            }
        }
        __syncthreads();
        if (t == 0) {                            // exclusive scan over 9 entries
            int run = 0;
#pragma unroll
            for (int i = 0; i < NG8 + 1; ++i) { int c = lcnt[i]; lcnt[i] = run; run += c; }
        }
        __syncthreads();
#pragma unroll
        for (int k = 0; k < 4; ++k)
            if (dd[k] >= 0)
                sorted[lcnt[bb[k]] + pp[k]] = ((unsigned)dd[k] << 16) | (unsigned)ss[k];
        __syncthreads();
        for (int j = t; j < ce; j += 256) staged[(size_t)bid * SCHUNK + j] = sorted[j];
        if (t < NG8 + 1) bofs[t * nsb + bid] = lcnt[t];
        return;
    }

    // ---------- gemm1 role: zero cnt slice; P1b = F @ W1 ----------
    int gb = bid - nsb;
    int zi = gb * 256 + t;
    if (zi < n_nodes) cnt[zi] = 0;
    {
        const float4* w4 = (const float4*)W1;
        float4* ws4 = (float4*)w;
#pragma unroll
        for (int j = 0; j < 8; ++j) ws4[t + 256 * j] = w4[t + 256 * j];
    }
    __syncthreads();
    int wid = t >> 6, lane = t & 63;
    int row0 = gb * 32 + wid * 8;
#pragma unroll
    for (int r = 0; r < 8; ++r) {
        int row = row0 + r;
        if (row >= n_nodes) break;
        const float4* f4 = (const float4*)(F + (size_t)row * NF);
        float acc = 0.f;
#pragma unroll 8
        for (int k4 = 0; k4 < NF / 4; ++k4) {
            float4 fv = f4[k4];
            acc += fv.x * w[(k4 * 4 + 0) * H1 + lane];
            acc += fv.y * w[(k4 * 4 + 1) * H1 + lane];
            acc += fv.z * w[(k4 * 4 + 2) * H1 + lane];
            acc += fv.w * w[(k4 * 4 + 3) * H1 + lane];
        }
        P1b[(size_t)row * H1 + lane] = f2b(acc);
    }
}

// ---- K2: fill2 — group g = bid&7 bins its bucket segments into XCD-local slots ----
__launch_bounds__(256)
__global__ void fill2_kernel(const unsigned* __restrict__ staged, const int* __restrict__ bofs,
                             int* __restrict__ cnt, unsigned short* __restrict__ slots,
                             int nsb) {
    int g = blockIdx.x & (NG8 - 1), gi = blockIdx.x >> 3;
    for (int sb = gi; sb < nsb; sb += FILL_BPG) {
        int st = bofs[g * nsb + sb];
        int en = bofs[(g + 1) * nsb + sb];
        const unsigned* seg = staged + (size_t)sb * SCHUNK;
        for (int j = st + threadIdx.x; j < en; j += 256) {
            unsigned u = seg[j];
            int d = u >> 16;
            int p = atomicAdd(&cnt[d], 1);
            if (p < CAP) slots[(d << CAPSH) + p] = (unsigned short)(u & 0xffffu);
        }
    }
}

// ---- K3: agg1 + bias + relu + gemm2 -> P2b. Wave per node; quarter-wave per edge;
// FOUR independent slot->row chains (stride 16). ----
__launch_bounds__(256)
__global__ void agg1gemm2_kernel(const unsigned short* __restrict__ P1b,
                                 const int* __restrict__ cnt, const unsigned short* __restrict__ slots,
                                 const float* __restrict__ b1, const float* __restrict__ W2,
                                 unsigned short* __restrict__ P2b, int n_nodes, int sz) {
    __shared__ float w2s[H1 * H2];   // 8 KB
    __shared__ float arow[4][H1];    // 1 KB
    {
        const float4* w4 = (const float4*)W2;
        float4* ws4 = (float4*)w2s;
#pragma unroll
        for (int j = 0; j < 2; ++j) ws4[threadIdx.x + 256 * j] = w4[threadIdx.x + 256 * j];
    }
    __syncthreads();
    int wid = threadIdx.x >> 6, lane = threadIdx.x & 63;
    int g = blockIdx.x & (NG8 - 1), gi = blockIdx.x >> 3;
    int ni = gi * 4 + wid;
    if (ni >= sz) return;
    int node = g * sz + ni;
    if (node >= n_nodes) return;
    int deg = min(cnt[node], CAP);
    int base = node << CAPSH;
    int q = lane >> 4, c = lane & 15;
    const uint2* P1v = (const uint2*)P1b;             // row = 16 uint2 (64 bf16)
    float a0=0.f,a1=0.f,a2=0.f,a3=0.f, b0=0.f,b1v=0.f,b2v=0.f,b3=0.f;
    float c0=0.f,c1=0.f,c2=0.f,c3=0.f, d0=0.f,d1=0.f,d2=0.f,d3=0.f;
    int i = 0;
    for (; i + 16 <= deg; i += 16) {                  // 4 independent chains
        int sA = slots[base + i + q];
        int sB = slots[base + i + 4 + q];
        int sC = slots[base + i + 8 + q];
        int sD = slots[base + i + 12 + q];
        uint2 uA = P1v[(sA << 4) + c];
        uint2 uB = P1v[(sB << 4) + c];
        uint2 uC = P1v[(sC << 4) + c];
        uint2 uD = P1v[(sD << 4) + c];
        a0 += blo(uA.x); a1 += bhi(uA.x); a2 += blo(uA.y); a3 += bhi(uA.y);
        b0 += blo(uB.x); b1v += bhi(uB.x); b2v += blo(uB.y); b3 += bhi(uB.y);
        c0 += blo(uC.x); c1 += bhi(uC.x); c2 += blo(uC.y); c3 += bhi(uC.y);
        d0 += blo(uD.x); d1 += bhi(uD.x); d2 += blo(uD.y); d3 += bhi(uD.y);
    }
    for (; i + 4 <= deg; i += 4) {
        int sA = slots[base + i + q];
        uint2 uA = P1v[(sA << 4) + c];
        a0 += blo(uA.x); a1 += bhi(uA.x); a2 += blo(uA.y); a3 += bhi(uA.y);
    }
    if (q < deg - i) {
        int sA = slots[base + i + q];
        uint2 uA = P1v[(sA << 4) + c];
        a0 += blo(uA.x); a1 += bhi(uA.x); a2 += blo(uA.y); a3 += bhi(uA.y);
    }
    a0 += b0 + c0 + d0; a1 += b1v + c1 + d1; a2 += b2v + c2 + d2; a3 += b3 + c3 + d3;
    a0 += __shfl_xor(a0, 16, 64); a0 += __shfl_xor(a0, 32, 64);
    a1 += __shfl_xor(a1, 16, 64); a1 += __shfl_xor(a1, 32, 64);
    a2 += __shfl_xor(a2, 16, 64); a2 += __shfl_xor(a2, 32, 64);
    a3 += __shfl_xor(a3, 16, 64); a3 += __shfl_xor(a3, 32, 64);
    if (q == 0) {
        float4 bb = *(const float4*)(b1 + 4 * c);
        float4 v;
        v.x = fmaxf(a0 + bb.x, 0.f);
        v.y = fmaxf(a1 + bb.y, 0.f);
        v.z = fmaxf(a2 + bb.z, 0.f);
        v.w = fmaxf(a3 + bb.w, 0.f);
        *(float4*)&arow[wid][4 * c] = v;
    }
    // wave-local LDS bounce (in-order within wave)
    int half = lane >> 5, c32 = lane & 31, kb = half * 32;
    float acc2 = 0.f;
#pragma unroll
    for (int k = 0; k < 32; ++k) acc2 += arow[wid][kb + k] * w2s[(kb + k) * H2 + c32];
    acc2 += __shfl_xor(acc2, 32, 64);
    if (lane < 32) P2b[(size_t)node * H2 + c32] = f2b(acc2);
}

// ---- K4: agg2 + bias -> out. Wave per node; eighth-wave per edge;
// FOUR independent chains (stride 32). ----
__launch_bounds__(256)
__global__ void agg2_kernel(const unsigned short* __restrict__ P2b,
                            const int* __restrict__ cnt, const unsigned short* __restrict__ slots,
                            const float* __restrict__ b2, float* __restrict__ out,
                            int n_nodes, int sz) {
    int wid = threadIdx.x >> 6, lane = threadIdx.x & 63;
    int g = blockIdx.x & (NG8 - 1), gi = blockIdx.x >> 3;
    int ni = gi * 4 + wid;
    if (ni >= sz) return;
    int node = g * sz + ni;
    if (node >= n_nodes) return;
    int deg = min(cnt[node], CAP);
    int base = node << CAPSH;
    int o = lane >> 3, c = lane & 7;
    const uint2* P2v = (const uint2*)P2b;             // row = 8 uint2 (32 bf16)
    float a0=0.f,a1=0.f,a2=0.f,a3=0.f, b0=0.f,b1v=0.f,b2v=0.f,b3=0.f;
    float c0=0.f,c1=0.f,c2=0.f,c3=0.f, d0=0.f,d1=0.f,d2=0.f,d3=0.f;
    int i = 0;
    for (; i + 32 <= deg; i += 32) {                  // 4 independent chains
        int sA = slots[base + i + o];
        int sB = slots[base + i + 8 + o];
        int sC = slots[base + i + 16 + o];
        int sD = slots[base + i + 24 + o];
        uint2 uA = P2v[(sA << 3) + c];
        uint2 uB = P2v[(sB << 3) + c];
        uint2 uC = P2v[(sC << 3) + c];
        uint2 uD = P2v[(sD << 3) + c];
        a0 += blo(uA.x); a1 += bhi(uA.x); a2 += blo(uA.y); a3 += bhi(uA.y);
        b0 += blo(uB.x); b1v += bhi(uB.x); b2v += blo(uB.y); b3 += bhi(uB.y);
        c0 += blo(uC.x); c1 += bhi(uC.x); c2 += blo(uC.y); c3 += bhi(uC.y);
        d0 += blo(uD.x); d1 += bhi(uD.x); d2 += blo(uD.y); d3 += bhi(uD.y);
    }
    for (; i + 8 <= deg; i += 8) {
        int sA = slots[base + i + o];
        uint2 uA = P2v[(sA << 3) + c];
        a0 += blo(uA.x); a1 += bhi(uA.x); a2 += blo(uA.y); a3 += bhi(uA.y);
    }
    if (o < deg - i) {
        int sA = slots[base + i + o];
        uint2 uA = P2v[(sA << 3) + c];
        a0 += blo(uA.x); a1 += bhi(uA.x); a2 += blo(uA.y); a3 += bhi(uA.y);
    }
    a0 += b0 + c0 + d0; a1 += b1v + c1 + d1; a2 += b2v + c2 + d2; a3 += b3 + c3 + d3;
    a0 += __shfl_xor(a0, 8, 64); a0 += __shfl_xor(a0, 16, 64); a0 += __shfl_xor(a0, 32, 64);
    a1 += __shfl_xor(a1, 8, 64); a1 += __shfl_xor(a1, 16, 64); a1 += __shfl_xor(a1, 32, 64);
    a2 += __shfl_xor(a2, 8, 64); a2 += __shfl_xor(a2, 16, 64); a2 += __shfl_xor(a2, 32, 64);
    a3 += __shfl_xor(a3, 8, 64); a3 += __shfl_xor(a3, 16, 64); a3 += __shfl_xor(a3, 32, 64);
    if (o == 0) {
        float4 bb = *(const float4*)(b2 + 4 * c);
        float4 v;
        v.x = a0 + bb.x; v.y = a1 + bb.y; v.z = a2 + bb.z; v.w = a3 + bb.w;
        *(float4*)(out + (size_t)node * H2 + 4 * c) = v;
    }
}

extern "C" void kernel_launch(void* const* d_in, const int* in_sizes, int n_in,
                              void* d_out, int out_size, void* d_ws, size_t ws_size,
                              hipStream_t stream) {
    const float* F  = (const float*)d_in[0];
    const float* W1 = (const float*)d_in[1];
    const float* b1 = (const float*)d_in[2];
    const float* W2 = (const float*)d_in[3];
    const float* b2 = (const float*)d_in[4];
    const int* src  = (const int*)d_in[5];
    const int* dst  = (const int*)d_in[6];
    float* out = (float*)d_out;

    int n_nodes = in_sizes[0] / NF;                       // 20000
    int n_edges = in_sizes[5];                            // 640000
    int sz = (n_nodes + NG8 - 1) / NG8;                   // nodes per group (2500)
    unsigned inv_sz = (unsigned)(((1ULL << 32) + sz - 1) / (unsigned)sz);
    int nsb = (n_edges + SCHUNK - 1) / SCHUNK;            // stage blocks (625)

    // Workspace layout (~11.6 MB):
    unsigned short* P1b = (unsigned short*)d_ws;              // [n][64] bf16   2.56 MB
    unsigned short* P2b = P1b + (size_t)n_nodes * H1;         // [n][32] bf16   1.28 MB
    unsigned short* slots = P2b + (size_t)n_nodes * H2;       // [n][CAP]       5.12 MB
    int* cnt = (int*)(slots + ((size_t)n_nodes << CAPSH));    // [n]            80 KB
    unsigned* staged = (unsigned*)(cnt + n_nodes);            // [nsb][1024]    2.56 MB
    int* bofs = (int*)(staged + (size_t)nsb * SCHUNK);        // [9][nsb]       22.5 KB

    int g1 = nsb + (n_nodes + 31) / 32;                       // 625 + 625
    k1_kernel<<<g1, 256, 0, stream>>>(F, W1, src, dst, staged, bofs, P1b, cnt,
                                      inv_sz, n_nodes, n_edges, nsb);
    fill2_kernel<<<FILL_BPG * NG8, 256, 0, stream>>>(staged, bofs, cnt, slots, nsb);
    int bpg = (sz + 3) / 4;
    agg1gemm2_kernel<<<bpg * NG8, 256, 0, stream>>>(P1b, cnt, slots, b1, W2, P2b, n_nodes, sz);
    agg2_kernel<<<bpg * NG8, 256, 0, stream>>>(P2b, cnt, slots, b2, out, n_nodes, sz);
}

// Round 10
// 90.431 us; speedup vs baseline: 5.6542x; 1.0713x over previous
//
#include <hip/hip_runtime.h>

// GCN: out = agg(relu(agg(F)@W1 + b1)) @ W2 + b2
// Reordered (agg linear): P1 = F@W1 (bf16); A1 = b1 + agg(P1); P2 = relu(A1)@W2 (bf16);
//                         out = b2 + agg(P2)
// Round-9 skeleton, k1 rebuilt (was 47.8us = half of total):
//  - gemm1 role: W1 column held in VGPRs (wreg[64] x 2 chunks) -> NO LDS read per FMA
//    (was 1024 ds_read/wave at ~5.8cyc = the serial resource), NO 32KB LDS block.
//  - stage role: ballot-based per-wave histogram (32 ballot+popc, wave-uniform scalar)
//    replaces 1024 LDS atomicAdds serialized onto 8 counters; LDS 33KB -> 4.4KB.
// Lessons kept: no grid.sync (r7), no per-window compaction (r8), XCD-local slot
// writes (r4: 59B HBM per 4B payload without), 4-chain ILP gathers (r9).

#define NF 128
#define H1 64
#define H2 32
#define CAP 128       // slot capacity/node; deg ~ Poisson(32), P(>128) ~ 1e-30; guarded
#define CAPSH 7
#define NG8 8         // node-range groups (== XCDs)
#define SCHUNK 1024   // edges per stage block
#define FILL_BPG 80   // fill2 blocks per group

__device__ __forceinline__ float blo(unsigned u){ return __uint_as_float(u << 16); }
__device__ __forceinline__ float bhi(unsigned u){ return __uint_as_float(u & 0xffff0000u); }
__device__ __forceinline__ unsigned short f2b(float f){   // fp32 -> bf16 RNE
    unsigned x = __float_as_uint(f);
    return (unsigned short)((x + 0x7fffu + ((x >> 16) & 1u)) >> 16);
}

// ---- K1: stage blocks (bid < nsb) + gemm1 blocks (bid >= nsb) ----
__launch_bounds__(256)
__global__ void k1_kernel(const float* __restrict__ F, const float* __restrict__ W1,
                          const int* __restrict__ src, const int* __restrict__ dst,
                          unsigned* __restrict__ staged, int* __restrict__ bofs,
                          unsigned short* __restrict__ P1b, int* __restrict__ cnt,
                          unsigned inv_sz, int n_nodes, int n_edges, int nsb) {
    __shared__ unsigned sorted[SCHUNK];      // 4 KB (stage role only)
    __shared__ int wcnt[4][NG8];
    __shared__ int wbase[4][NG8];
    __shared__ int bb0[NG8 + 1];
    const int t = threadIdx.x;
    const int bid = blockIdx.x;
    const int wid = t >> 6, lane = t & 63;

    if (bid < nsb) {
        // ---------- stage role: sort my 1024-edge chunk by XCD-group bucket ----------
        int e0 = bid * SCHUNK;
        int ce = min(n_edges - e0, SCHUNK);
        int i4 = e0 + t * 4;
        int dd[4], ss[4], bb[4], pp[4];
        bool val[4];
        if (i4 + 4 <= n_edges) {
            int4 d4 = *(const int4*)(dst + i4);
            int4 s4 = *(const int4*)(src + i4);
            dd[0]=d4.x; dd[1]=d4.y; dd[2]=d4.z; dd[3]=d4.w;
            ss[0]=s4.x; ss[1]=s4.y; ss[2]=s4.z; ss[3]=s4.w;
        } else {
#pragma unroll
            for (int k = 0; k < 4; ++k) {
                int e = i4 + k;
                dd[k] = (e < n_edges) ? dst[e] : -1;
                ss[k] = (e < n_edges) ? src[e] : 0;
            }
        }
        unsigned long long lt = (1ULL << lane) - 1ULL;
#pragma unroll
        for (int k = 0; k < 4; ++k) {
            val[k] = dd[k] >= 0;
            bb[k] = val[k]
                ? (int)(unsigned)(((unsigned long long)(unsigned)dd[k] * inv_sz) >> 32)
                : 0;
        }
        // per-wave ballot histogram + rank (no LDS atomics)
#pragma unroll
        for (int b = 0; b < NG8; ++b) {
            int running = 0;
#pragma unroll
            for (int k = 0; k < 4; ++k) {
                unsigned long long m = __ballot(val[k] && (bb[k] == b));
                if (val[k] && (bb[k] == b)) pp[k] = running + (int)__popcll(m & lt);
                running += (int)__popcll(m);
            }
            if (lane == 0) wcnt[wid][b] = running;
        }
        __syncthreads();
        if (t < NG8) {                           // combine 4 waves per bucket
            int tot = 0;
#pragma unroll
            for (int w = 0; w < 4; ++w) { wbase[w][t] = tot; tot += wcnt[w][t]; }
            bb0[t] = tot;                        // block total for bucket t (pre-scan)
        }
        __syncthreads();
        if (t == 0) {                            // exclusive scan over 8 buckets
            int run = 0;
#pragma unroll
            for (int b = 0; b < NG8; ++b) { int c = bb0[b]; bb0[b] = run; run += c; }
            bb0[NG8] = run;
        }
        __syncthreads();
#pragma unroll
        for (int k = 0; k < 4; ++k)
            if (val[k])
                sorted[bb0[bb[k]] + wbase[wid][bb[k]] + pp[k]] =
                    ((unsigned)dd[k] << 16) | (unsigned)ss[k];
        __syncthreads();
        for (int j = t; j < ce; j += 256) staged[(size_t)bid * SCHUNK + j] = sorted[j];
        if (t < NG8 + 1) bofs[t * nsb + bid] = bb0[t];
        return;
    }

    // ---------- gemm1 role: zero cnt slice; P1b = F @ W1 with W1 in VGPRs ----------
    int gb = bid - nsb;
    int zi = gb * 256 + t;
    if (zi < n_nodes) cnt[zi] = 0;
    int row0 = gb * 32 + wid * 8;
    float acc[8] = {0.f, 0.f, 0.f, 0.f, 0.f, 0.f, 0.f, 0.f};
#pragma unroll 1
    for (int cc = 0; cc < 2; ++cc) {             // two 64-k chunks (caps VGPR use)
        const int c0 = cc * 64;
        float wreg[64];                          // my column's 64 weights, in registers
#pragma unroll
        for (int k = 0; k < 64; ++k) wreg[k] = W1[(c0 + k) * H1 + lane];
#pragma unroll
        for (int r = 0; r < 8; ++r) {
            int row = row0 + r;
            if (row < n_nodes) {
                const float4* f4 = (const float4*)(F + (size_t)row * NF + c0);
#pragma unroll
                for (int k4 = 0; k4 < 16; ++k4) {
                    float4 fv = f4[k4];
                    acc[r] += fv.x * wreg[k4 * 4 + 0];
                    acc[r] += fv.y * wreg[k4 * 4 + 1];
                    acc[r] += fv.z * wreg[k4 * 4 + 2];
                    acc[r] += fv.w * wreg[k4 * 4 + 3];
                }
            }
        }
    }
#pragma unroll
    for (int r = 0; r < 8; ++r) {
        int row = row0 + r;
        if (row < n_nodes) P1b[(size_t)row * H1 + lane] = f2b(acc[r]);
    }
}

// ---- K2: fill2 — group g = bid&7 bins its bucket segments into XCD-local slots ----
__launch_bounds__(256)
__global__ void fill2_kernel(const unsigned* __restrict__ staged, const int* __restrict__ bofs,
                             int* __restrict__ cnt, unsigned short* __restrict__ slots,
                             int nsb) {
    int g = blockIdx.x & (NG8 - 1), gi = blockIdx.x >> 3;
    for (int sb = gi; sb < nsb; sb += FILL_BPG) {
        int st = bofs[g * nsb + sb];
        int en = bofs[(g + 1) * nsb + sb];
        const unsigned* seg = staged + (size_t)sb * SCHUNK;
        for (int j = st + threadIdx.x; j < en; j += 256) {
            unsigned u = seg[j];
            int d = u >> 16;
            int p = atomicAdd(&cnt[d], 1);
            if (p < CAP) slots[(d << CAPSH) + p] = (unsigned short)(u & 0xffffu);
        }
    }
}

// ---- K3: agg1 + bias + relu + gemm2 -> P2b. Wave per node; quarter-wave per edge;
// FOUR independent slot->row chains (stride 16). ----
__launch_bounds__(256)
__global__ void agg1gemm2_kernel(const unsigned short* __restrict__ P1b,
                                 const int* __restrict__ cnt, const unsigned short* __restrict__ slots,
                                 const float* __restrict__ b1, const float* __restrict__ W2,
                                 unsigned short* __restrict__ P2b, int n_nodes, int sz) {
    __shared__ float w2s[H1 * H2];   // 8 KB
    __shared__ float arow[4][H1];    // 1 KB
    {
        const float4* w4 = (const float4*)W2;
        float4* ws4 = (float4*)w2s;
#pragma unroll
        for (int j = 0; j < 2; ++j) ws4[threadIdx.x + 256 * j] = w4[threadIdx.x + 256 * j];
    }
    __syncthreads();
    int wid = threadIdx.x >> 6, lane = threadIdx.x & 63;
    int g = blockIdx.x & (NG8 - 1), gi = blockIdx.x >> 3;
    int ni = gi * 4 + wid;
    if (ni >= sz) return;
    int node = g * sz + ni;
    if (node >= n_nodes) return;
    int deg = min(cnt[node], CAP);
    int base = node << CAPSH;
    int q = lane >> 4, c = lane & 15;
    const uint2* P1v = (const uint2*)P1b;             // row = 16 uint2 (64 bf16)
    float a0=0.f,a1=0.f,a2=0.f,a3=0.f, b0=0.f,b1v=0.f,b2v=0.f,b3=0.f;
    float c0=0.f,c1=0.f,c2=0.f,c3=0.f, d0=0.f,d1=0.f,d2=0.f,d3=0.f;
    int i = 0;
    for (; i + 16 <= deg; i += 16) {                  // 4 independent chains
        int sA = slots[base + i + q];
        int sB = slots[base + i + 4 + q];
        int sC = slots[base + i + 8 + q];
        int sD = slots[base + i + 12 + q];
        uint2 uA = P1v[(sA << 4) + c];
        uint2 uB = P1v[(sB << 4) + c];
        uint2 uC = P1v[(sC << 4) + c];
        uint2 uD = P1v[(sD << 4) + c];
        a0 += blo(uA.x); a1 += bhi(uA.x); a2 += blo(uA.y); a3 += bhi(uA.y);
        b0 += blo(uB.x); b1v += bhi(uB.x); b2v += blo(uB.y); b3 += bhi(uB.y);
        c0 += blo(uC.x); c1 += bhi(uC.x); c2 += blo(uC.y); c3 += bhi(uC.y);
        d0 += blo(uD.x); d1 += bhi(uD.x); d2 += blo(uD.y); d3 += bhi(uD.y);
    }
    for (; i + 4 <= deg; i += 4) {
        int sA = slots[base + i + q];
        uint2 uA = P1v[(sA << 4) + c];
        a0 += blo(uA.x); a1 += bhi(uA.x); a2 += blo(uA.y); a3 += bhi(uA.y);
    }
    if (q < deg - i) {
        int sA = slots[base + i + q];
        uint2 uA = P1v[(sA << 4) + c];
        a0 += blo(uA.x); a1 += bhi(uA.x); a2 += blo(uA.y); a3 += bhi(uA.y);
    }
    a0 += b0 + c0 + d0; a1 += b1v + c1 + d1; a2 += b2v + c2 + d2; a3 += b3 + c3 + d3;
    a0 += __shfl_xor(a0, 16, 64); a0 += __shfl_xor(a0, 32, 64);
    a1 += __shfl_xor(a1, 16, 64); a1 += __shfl_xor(a1, 32, 64);
    a2 += __shfl_xor(a2, 16, 64); a2 += __shfl_xor(a2, 32, 64);
    a3 += __shfl_xor(a3, 16, 64); a3 += __shfl_xor(a3, 32, 64);
    if (q == 0) {
        float4 bb = *(const float4*)(b1 + 4 * c);
        float4 v;
        v.x = fmaxf(a0 + bb.x, 0.f);
        v.y = fmaxf(a1 + bb.y, 0.f);
        v.z = fmaxf(a2 + bb.z, 0.f);
        v.w = fmaxf(a3 + bb.w, 0.f);
        *(float4*)&arow[wid][4 * c] = v;
    }
    // wave-local LDS bounce (in-order within wave)
    int half = lane >> 5, c32 = lane & 31, kb = half * 32;
    float acc2 = 0.f;
#pragma unroll
    for (int k = 0; k < 32; ++k) acc2 += arow[wid][kb + k] * w2s[(kb + k) * H2 + c32];
    acc2 += __shfl_xor(acc2, 32, 64);
    if (lane < 32) P2b[(size_t)node * H2 + c32] = f2b(acc2);
}

// ---- K4: agg2 + bias -> out. Wave per node; eighth-wave per edge;
// FOUR independent chains (stride 32). ----
__launch_bounds__(256)
__global__ void agg2_kernel(const unsigned short* __restrict__ P2b,
                            const int* __restrict__ cnt, const unsigned short* __restrict__ slots,
                            const float* __restrict__ b2, float* __restrict__ out,
                            int n_nodes, int sz) {
    int wid = threadIdx.x >> 6, lane = threadIdx.x & 63;
    int g = blockIdx.x & (NG8 - 1), gi = blockIdx.x >> 3;
    int ni = gi * 4 + wid;
    if (ni >= sz) return;
    int node = g * sz + ni;
    if (node >= n_nodes) return;
    int deg = min(cnt[node], CAP);
    int base = node << CAPSH;
    int o = lane >> 3, c = lane & 7;
    const uint2* P2v = (const uint2*)P2b;             // row = 8 uint2 (32 bf16)
    float a0=0.f,a1=0.f,a2=0.f,a3=0.f, b0=0.f,b1v=0.f,b2v=0.f,b3=0.f;
    float c0=0.f,c1=0.f,c2=0.f,c3=0.f, d0=0.f,d1=0.f,d2=0.f,d3=0.f;
    int i = 0;
    for (; i + 32 <= deg; i += 32) {                  // 4 independent chains
        int sA = slots[base + i + o];
        int sB = slots[base + i + 8 + o];
        int sC = slots[base + i + 16 + o];
        int sD = slots[base + i + 24 + o];
        uint2 uA = P2v[(sA << 3) + c];
        uint2 uB = P2v[(sB << 3) + c];
        uint2 uC = P2v[(sC << 3) + c];
        uint2 uD = P2v[(sD << 3) + c];
        a0 += blo(uA.x); a1 += bhi(uA.x); a2 += blo(uA.y); a3 += bhi(uA.y);
        b0 += blo(uB.x); b1v += bhi(uB.x); b2v += blo(uB.y); b3 += bhi(uB.y);
        c0 += blo(uC.x); c1 += bhi(uC.x); c2 += blo(uC.y); c3 += bhi(uC.y);
        d0 += blo(uD.x); d1 += bhi(uD.x); d2 += blo(uD.y); d3 += bhi(uD.y);
    }
    for (; i + 8 <= deg; i += 8) {
        int sA = slots[base + i + o];
        uint2 uA = P2v[(sA << 3) + c];
        a0 += blo(uA.x); a1 += bhi(uA.x); a2 += blo(uA.y); a3 += bhi(uA.y);
    }
    if (o < deg - i) {
        int sA = slots[base + i + o];
        uint2 uA = P2v[(sA << 3) + c];
        a0 += blo(uA.x); a1 += bhi(uA.x); a2 += blo(uA.y); a3 += bhi(uA.y);
    }
    a0 += b0 + c0 + d0; a1 += b1v + c1 + d1; a2 += b2v + c2 + d2; a3 += b3 + c3 + d3;
    a0 += __shfl_xor(a0, 8, 64); a0 += __shfl_xor(a0, 16, 64); a0 += __shfl_xor(a0, 32, 64);
    a1 += __shfl_xor(a1, 8, 64); a1 += __shfl_xor(a1, 16, 64); a1 += __shfl_xor(a1, 32, 64);
    a2 += __shfl_xor(a2, 8, 64); a2 += __shfl_xor(a2, 16, 64); a2 += __shfl_xor(a2, 32, 64);
    a3 += __shfl_xor(a3, 8, 64); a3 += __shfl_xor(a3, 16, 64); a3 += __shfl_xor(a3, 32, 64);
    if (o == 0) {
        float4 bb = *(const float4*)(b2 + 4 * c);
        float4 v;
        v.x = a0 + bb.x; v.y = a1 + bb.y; v.z = a2 + bb.z; v.w = a3 + bb.w;
        *(float4*)(out + (size_t)node * H2 + 4 * c) = v;
    }
}

extern "C" void kernel_launch(void* const* d_in, const int* in_sizes, int n_in,
                              void* d_out, int out_size, void* d_ws, size_t ws_size,
                              hipStream_t stream) {
    const float* F  = (const float*)d_in[0];
    const float* W1 = (const float*)d_in[1];
    const float* b1 = (const float*)d_in[2];
    const float* W2 = (const float*)d_in[3];
    const float* b2 = (const float*)d_in[4];
    const int* src  = (const int*)d_in[5];
    const int* dst  = (const int*)d_in[6];
    float* out = (float*)d_out;

    int n_nodes = in_sizes[0] / NF;                       // 20000
    int n_edges = in_sizes[5];                            // 640000
    int sz = (n_nodes + NG8 - 1) / NG8;                   // nodes per group (2500)
    unsigned inv_sz = (unsigned)(((1ULL << 32) + sz - 1) / (unsigned)sz);
    int nsb = (n_edges + SCHUNK - 1) / SCHUNK;            // stage blocks (625)

    // Workspace layout (~11.6 MB):
    unsigned short* P1b = (unsigned short*)d_ws;              // [n][64] bf16   2.56 MB
    unsigned short* P2b = P1b + (size_t)n_nodes * H1;         // [n][32] bf16   1.28 MB
    unsigned short* slots = P2b + (size_t)n_nodes * H2;       // [n][CAP]       5.12 MB
    int* cnt = (int*)(slots + ((size_t)n_nodes << CAPSH));    // [n]            80 KB
    unsigned* staged = (unsigned*)(cnt + n_nodes);            // [nsb][1024]    2.56 MB
    int* bofs = (int*)(staged + (size_t)nsb * SCHUNK);        // [9][nsb]       22.5 KB

    int g1 = nsb + (n_nodes + 31) / 32;                       // 625 + 625
    k1_kernel<<<g1, 256, 0, stream>>>(F, W1, src, dst, staged, bofs, P1b, cnt,
                                      inv_sz, n_nodes, n_edges, nsb);
    fill2_kernel<<<FILL_BPG * NG8, 256, 0, stream>>>(staged, bofs, cnt, slots, nsb);
    int bpg = (sz + 3) / 4;
    agg1gemm2_kernel<<<bpg * NG8, 256, 0, stream>>>(P1b, cnt, slots, b1, W2, P2b, n_nodes, sz);
    agg2_kernel<<<bpg * NG8, 256, 0, stream>>>(P2b, cnt, slots, b2, out, n_nodes, sz);
}

// Round 13
// 88.967 us; speedup vs baseline: 5.7472x; 1.0165x over previous
//
#include <hip/hip_runtime.h>

// GCN: out = agg(relu(agg(F)@W1 + b1)) @ W2 + b2
// Reordered (agg linear): P1 = F@W1 (bf16); A1 = b1 + agg(P1); P2 = relu(A1)@W2 (bf16);
//                         out = b2 + agg(P2)
// r10 skeleton + agg shfl-prefetch, with the r11/r12 bug FIXED:
//   __shfl = ds_bpermute (PULL) -> data from an EXEC-masked-off source lane is
//   UNDEFINED. r12 called __shfl inside the divergent remainder guard, pulling
//   from inactive lanes -> garbage slot ids (absmax ~80). Fix: hoist the shfl
//   ABOVE the guard (all 64 lanes execute; srcLane = i+q <= 63 always since the
//   loop leaves i a multiple of 4/8 <= 60/56); only the gather+add is guarded.
// Lessons kept: no grid.sync (r7), no per-window compaction (r8), XCD-local slot
// writes (r4), ballot histogram + reg-W1 (r10).

#define NF 128
#define H1 64
#define H2 32
#define CAP 128       // slot capacity/node; deg ~ Poisson(32), P(>128) ~ 1e-30; guarded
#define CAPSH 7
#define NG8 8         // node-range groups (== XCDs)
#define SCHUNK 1024   // edges per stage block
#define FILL_BPG 80   // fill2 blocks per group

__device__ __forceinline__ float blo(unsigned u){ return __uint_as_float(u << 16); }
__device__ __forceinline__ float bhi(unsigned u){ return __uint_as_float(u & 0xffff0000u); }
__device__ __forceinline__ unsigned short f2b(float f){   // fp32 -> bf16 RNE
    unsigned x = __float_as_uint(f);
    return (unsigned short)((x + 0x7fffu + ((x >> 16) & 1u)) >> 16);
}

// ---- K1: stage blocks (bid < nsb) + gemm1 blocks (bid >= nsb) ---- (r10 verbatim)
__launch_bounds__(256)
__global__ void k1_kernel(const float* __restrict__ F, const float* __restrict__ W1,
                          const int* __restrict__ src, const int* __restrict__ dst,
                          unsigned* __restrict__ staged, int* __restrict__ bofs,
                          unsigned short* __restrict__ P1b, int* __restrict__ cnt,
                          unsigned inv_sz, int n_nodes, int n_edges, int nsb) {
    __shared__ unsigned sorted[SCHUNK];      // 4 KB (stage role only)
    __shared__ int wcnt[4][NG8];
    __shared__ int wbase[4][NG8];
    __shared__ int bb0[NG8 + 1];
    const int t = threadIdx.x;
    const int bid = blockIdx.x;
    const int wid = t >> 6, lane = t & 63;

    if (bid < nsb) {
        // ---------- stage role: sort my 1024-edge chunk by XCD-group bucket ----------
        int e0 = bid * SCHUNK;
        int ce = min(n_edges - e0, SCHUNK);
        int i4 = e0 + t * 4;
        int dd[4], ss[4], bb[4], pp[4];
        bool val[4];
        if (i4 + 4 <= n_edges) {
            int4 d4 = *(const int4*)(dst + i4);
            int4 s4 = *(const int4*)(src + i4);
            dd[0]=d4.x; dd[1]=d4.y; dd[2]=d4.z; dd[3]=d4.w;
            ss[0]=s4.x; ss[1]=s4.y; ss[2]=s4.z; ss[3]=s4.w;
        } else {
#pragma unroll
            for (int k = 0; k < 4; ++k) {
                int e = i4 + k;
                dd[k] = (e < n_edges) ? dst[e] : -1;
                ss[k] = (e < n_edges) ? src[e] : 0;
            }
        }
        unsigned long long lt = (1ULL << lane) - 1ULL;
#pragma unroll
        for (int k = 0; k < 4; ++k) {
            val[k] = dd[k] >= 0;
            bb[k] = val[k]
                ? (int)(unsigned)(((unsigned long long)(unsigned)dd[k] * inv_sz) >> 32)
                : 0;
        }
        // per-wave ballot histogram + rank (no LDS atomics)
#pragma unroll
        for (int b = 0; b < NG8; ++b) {
            int running = 0;
#pragma unroll
            for (int k = 0; k < 4; ++k) {
                unsigned long long m = __ballot(val[k] && (bb[k] == b));
                if (val[k] && (bb[k] == b)) pp[k] = running + (int)__popcll(m & lt);
                running += (int)__popcll(m);
            }
            if (lane == 0) wcnt[wid][b] = running;
        }
        __syncthreads();
        if (t < NG8) {                           // combine 4 waves per bucket
            int tot = 0;
#pragma unroll
            for (int w = 0; w < 4; ++w) { wbase[w][t] = tot; tot += wcnt[w][t]; }
            bb0[t] = tot;
        }
        __syncthreads();
        if (t == 0) {                            // exclusive scan over 8 buckets
            int run = 0;
#pragma unroll
            for (int b = 0; b < NG8; ++b) { int c = bb0[b]; bb0[b] = run; run += c; }
            bb0[NG8] = run;
        }
        __syncthreads();
#pragma unroll
        for (int k = 0; k < 4; ++k)
            if (val[k])
                sorted[bb0[bb[k]] + wbase[wid][bb[k]] + pp[k]] =
                    ((unsigned)dd[k] << 16) | (unsigned)ss[k];
        __syncthreads();
        for (int j = t; j < ce; j += 256) staged[(size_t)bid * SCHUNK + j] = sorted[j];
        if (t < NG8 + 1) bofs[t * nsb + bid] = bb0[t];
        return;
    }

    // ---------- gemm1 role: zero cnt slice; P1b = F @ W1 (W1 col in VGPRs) ----------
    int gb = bid - nsb;
    int zi = gb * 256 + t;
    if (zi < n_nodes) cnt[zi] = 0;
    int row0 = gb * 32 + wid * 8;
    float acc[8] = {0.f, 0.f, 0.f, 0.f, 0.f, 0.f, 0.f, 0.f};
#pragma unroll 1
    for (int cc = 0; cc < 2; ++cc) {             // two 64-k chunks (caps VGPR use)
        const int c0 = cc * 64;
        float wreg[64];                          // my column's 64 weights, in registers
#pragma unroll
        for (int k = 0; k < 64; ++k) wreg[k] = W1[(c0 + k) * H1 + lane];
#pragma unroll
        for (int r = 0; r < 8; ++r) {
            int row = row0 + r;
            if (row < n_nodes) {
                const float4* f4 = (const float4*)(F + (size_t)row * NF + c0);
#pragma unroll
                for (int k4 = 0; k4 < 16; ++k4) {
                    float4 fv = f4[k4];
                    acc[r] += fv.x * wreg[k4 * 4 + 0];
                    acc[r] += fv.y * wreg[k4 * 4 + 1];
                    acc[r] += fv.z * wreg[k4 * 4 + 2];
                    acc[r] += fv.w * wreg[k4 * 4 + 3];
                }
            }
        }
    }
#pragma unroll
    for (int r = 0; r < 8; ++r) {
        int row = row0 + r;
        if (row < n_nodes) P1b[(size_t)row * H1 + lane] = f2b(acc[r]);
    }
}

// ---- K2: fill2 — group g = bid&7 bins its bucket segments into XCD-local slots ----
// (r10 verbatim)
__launch_bounds__(256)
__global__ void fill2_kernel(const unsigned* __restrict__ staged, const int* __restrict__ bofs,
                             int* __restrict__ cnt, unsigned short* __restrict__ slots,
                             int nsb) {
    int g = blockIdx.x & (NG8 - 1), gi = blockIdx.x >> 3;
    for (int sb = gi; sb < nsb; sb += FILL_BPG) {
        int st = bofs[g * nsb + sb];
        int en = bofs[(g + 1) * nsb + sb];
        const unsigned* seg = staged + (size_t)sb * SCHUNK;
        for (int j = st + threadIdx.x; j < en; j += 256) {
            unsigned u = seg[j];
            int d = u >> 16;
            int p = atomicAdd(&cnt[d], 1);
            if (p < CAP) slots[(d << CAPSH) + p] = (unsigned short)(u & 0xffffu);
        }
    }
}

// ---- K3: agg1 + bias + relu + gemm2 -> P2b. Wave per node; quarter-wave per edge.
// Slot ids prefetched (one coalesced 128B load) + __shfl broadcast; ALL shfls run
// with the full wave active (bpermute from inactive lanes is undefined). ----
__launch_bounds__(256)
__global__ void agg1gemm2_kernel(const unsigned short* __restrict__ P1b,
                                 const int* __restrict__ cnt, const unsigned short* __restrict__ slots,
                                 const float* __restrict__ b1, const float* __restrict__ W2,
                                 unsigned short* __restrict__ P2b, int n_nodes, int sz) {
    __shared__ float w2s[H1 * H2];   // 8 KB
    __shared__ float arow[4][H1];    // 1 KB
    {
        const float4* w4 = (const float4*)W2;
        float4* ws4 = (float4*)w2s;
#pragma unroll
        for (int j = 0; j < 2; ++j) ws4[threadIdx.x + 256 * j] = w4[threadIdx.x + 256 * j];
    }
    __syncthreads();
    int wid = threadIdx.x >> 6, lane = threadIdx.x & 63;
    int g = blockIdx.x & (NG8 - 1), gi = blockIdx.x >> 3;
    int ni = gi * 4 + wid;
    if (ni >= sz) return;
    int node = g * sz + ni;
    if (node >= n_nodes) return;
    int deg = min(cnt[node], CAP);
    int base = node << CAPSH;
    int q = lane >> 4, c = lane & 15;
    int mys = (lane < deg) ? (int)slots[base + lane] : 0;   // one coalesced 128B load
    int dmain = min(deg, 64);
    const uint2* P1v = (const uint2*)P1b;             // row = 16 uint2 (64 bf16)
    float a0=0.f,a1=0.f,a2=0.f,a3=0.f, b0=0.f,b1v=0.f,b2v=0.f,b3=0.f;
    float c0=0.f,c1=0.f,c2=0.f,c3=0.f, d0=0.f,d1=0.f,d2=0.f,d3=0.f;
    int i = 0;
    for (; i + 16 <= dmain; i += 16) {                // full wave active: shfl safe
        int sA = __shfl(mys, i + q, 64);
        int sB = __shfl(mys, i + 4 + q, 64);
        int sC = __shfl(mys, i + 8 + q, 64);
        int sD = __shfl(mys, i + 12 + q, 64);
        uint2 uA = P1v[(sA << 4) + c];
        uint2 uB = P1v[(sB << 4) + c];
        uint2 uC = P1v[(sC << 4) + c];
        uint2 uD = P1v[(sD << 4) + c];
        a0 += blo(uA.x); a1 += bhi(uA.x); a2 += blo(uA.y); a3 += bhi(uA.y);
        b0 += blo(uB.x); b1v += bhi(uB.x); b2v += blo(uB.y); b3 += bhi(uB.y);
        c0 += blo(uC.x); c1 += bhi(uC.x); c2 += blo(uC.y); c3 += bhi(uC.y);
        d0 += blo(uD.x); d1 += bhi(uD.x); d2 += blo(uD.y); d3 += bhi(uD.y);
    }
    for (; i + 4 <= dmain; i += 4) {                  // full wave active: shfl safe
        int sA = __shfl(mys, i + q, 64);
        uint2 uA = P1v[(sA << 4) + c];
        a0 += blo(uA.x); a1 += bhi(uA.x); a2 += blo(uA.y); a3 += bhi(uA.y);
    }
    {   // partial last group: shfl HOISTED above the divergent guard (i+q <= 63 here)
        int sA = __shfl(mys, i + q, 64);
        if (q < dmain - i) {
            uint2 uA = P1v[(sA << 4) + c];
            a0 += blo(uA.x); a1 += bhi(uA.x); a2 += blo(uA.y); a3 += bhi(uA.y);
        }
    }
    for (int j = 64 + q; j < deg; j += 4) {           // rare deg>64 tail, direct loads
        int sA = slots[base + j];
        uint2 uA = P1v[(sA << 4) + c];
        a0 += blo(uA.x); a1 += bhi(uA.x); a2 += blo(uA.y); a3 += bhi(uA.y);
    }
    a0 += b0 + c0 + d0; a1 += b1v + c1 + d1; a2 += b2v + c2 + d2; a3 += b3 + c3 + d3;
    a0 += __shfl_xor(a0, 16, 64); a0 += __shfl_xor(a0, 32, 64);
    a1 += __shfl_xor(a1, 16, 64); a1 += __shfl_xor(a1, 32, 64);
    a2 += __shfl_xor(a2, 16, 64); a2 += __shfl_xor(a2, 32, 64);
    a3 += __shfl_xor(a3, 16, 64); a3 += __shfl_xor(a3, 32, 64);
    if (q == 0) {
        float4 bb = *(const float4*)(b1 + 4 * c);
        float4 v;
        v.x = fmaxf(a0 + bb.x, 0.f);
        v.y = fmaxf(a1 + bb.y, 0.f);
        v.z = fmaxf(a2 + bb.z, 0.f);
        v.w = fmaxf(a3 + bb.w, 0.f);
        *(float4*)&arow[wid][4 * c] = v;
    }
    // wave-local LDS bounce (in-order within wave)
    int half = lane >> 5, c32 = lane & 31, kb = half * 32;
    float acc2 = 0.f;
#pragma unroll
    for (int k = 0; k < 32; ++k) acc2 += arow[wid][kb + k] * w2s[(kb + k) * H2 + c32];
    acc2 += __shfl_xor(acc2, 32, 64);
    if (lane < 32) P2b[(size_t)node * H2 + c32] = f2b(acc2);
}

// ---- K4: agg2 + bias -> out. Wave per node; eighth-wave per edge; shfl prefetch
// with full-wave-active shfls (hoisted remainder). ----
__launch_bounds__(256)
__global__ void agg2_kernel(const unsigned short* __restrict__ P2b,
                            const int* __restrict__ cnt, const unsigned short* __restrict__ slots,
                            const float* __restrict__ b2, float* __restrict__ out,
                            int n_nodes, int sz) {
    int wid = threadIdx.x >> 6, lane = threadIdx.x & 63;
    int g = blockIdx.x & (NG8 - 1), gi = blockIdx.x >> 3;
    int ni = gi * 4 + wid;
    if (ni >= sz) return;
    int node = g * sz + ni;
    if (node >= n_nodes) return;
    int deg = min(cnt[node], CAP);
    int base = node << CAPSH;
    int o = lane >> 3, c = lane & 7;
    int mys = (lane < deg) ? (int)slots[base + lane] : 0;   // one coalesced load
    int dmain = min(deg, 64);
    const uint2* P2v = (const uint2*)P2b;             // row = 8 uint2 (32 bf16)
    float a0=0.f,a1=0.f,a2=0.f,a3=0.f, b0=0.f,b1v=0.f,b2v=0.f,b3=0.f;
    float c0=0.f,c1=0.f,c2=0.f,c3=0.f, d0=0.f,d1=0.f,d2=0.f,d3=0.f;
    int i = 0;
    for (; i + 32 <= dmain; i += 32) {                // full wave active: shfl safe
        int sA = __shfl(mys, i + o, 64);
        int sB = __shfl(mys, i + 8 + o, 64);
        int sC = __shfl(mys, i + 16 + o, 64);
        int sD = __shfl(mys, i + 24 + o, 64);
        uint2 uA = P2v[(sA << 3) + c];
        uint2 uB = P2v[(sB << 3) + c];
        uint2 uC = P2v[(sC << 3) + c];
        uint2 uD = P2v[(sD << 3) + c];
        a0 += blo(uA.x); a1 += bhi(uA.x); a2 += blo(uA.y); a3 += bhi(uA.y);
        b0 += blo(uB.x); b1v += bhi(uB.x); b2v += blo(uB.y); b3 += bhi(uB.y);
        c0 += blo(uC.x); c1 += bhi(uC.x); c2 += blo(uC.y); c3 += bhi(uC.y);
        d0 += blo(uD.x); d1 += bhi(uD.x); d2 += blo(uD.y); d3 += bhi(uD.y);
    }
    for (; i + 8 <= dmain; i += 8) {                  // full wave active: shfl safe
        int sA = __shfl(mys, i + o, 64);
        uint2 uA = P2v[(sA << 3) + c];
        a0 += blo(uA.x); a1 += bhi(uA.x); a2 += blo(uA.y); a3 += bhi(uA.y);
    }
    {   // partial last group: shfl HOISTED above the divergent guard (i+o <= 63 here)
        int sA = __shfl(mys, i + o, 64);
        if (o < dmain - i) {
            uint2 uA = P2v[(sA << 3) + c];
            a0 += blo(uA.x); a1 += bhi(uA.x); a2 += blo(uA.y); a3 += bhi(uA.y);
        }
    }
    for (int j = 64 + o; j < deg; j += 8) {           // rare deg>64 tail
        int sA = slots[base + j];
        uint2 uA = P2v[(sA << 3) + c];
        a0 += blo(uA.x); a1 += bhi(uA.x); a2 += blo(uA.y); a3 += bhi(uA.y);
    }
    a0 += b0 + c0 + d0; a1 += b1v + c1 + d1; a2 += b2v + c2 + d2; a3 += b3 + c3 + d3;
    a0 += __shfl_xor(a0, 8, 64); a0 += __shfl_xor(a0, 16, 64); a0 += __shfl_xor(a0, 32, 64);
    a1 += __shfl_xor(a1, 8, 64); a1 += __shfl_xor(a1, 16, 64); a1 += __shfl_xor(a1, 32, 64);
    a2 += __shfl_xor(a2, 8, 64); a2 += __shfl_xor(a2, 16, 64); a2 += __shfl_xor(a2, 32, 64);
    a3 += __shfl_xor(a3, 8, 64); a3 += __shfl_xor(a3, 16, 64); a3 += __shfl_xor(a3, 32, 64);
    if (o == 0) {
        float4 bb = *(const float4*)(b2 + 4 * c);
        float4 v;
        v.x = a0 + bb.x; v.y = a1 + bb.y; v.z = a2 + bb.z; v.w = a3 + bb.w;
        *(float4*)(out + (size_t)node * H2 + 4 * c) = v;
    }
}

extern "C" void kernel_launch(void* const* d_in, const int* in_sizes, int n_in,
                              void* d_out, int out_size, void* d_ws, size_t ws_size,
                              hipStream_t stream) {
    const float* F  = (const float*)d_in[0];
    const float* W1 = (const float*)d_in[1];
    const float* b1 = (const float*)d_in[2];
    const float* W2 = (const float*)d_in[3];
    const float* b2 = (const float*)d_in[4];
    const int* src  = (const int*)d_in[5];
    const int* dst  = (const int*)d_in[6];
    float* out = (float*)d_out;

    int n_nodes = in_sizes[0] / NF;                       // 20000
    int n_edges = in_sizes[5];                            // 640000
    int sz = (n_nodes + NG8 - 1) / NG8;                   // nodes per group (2500)
    unsigned inv_sz = (unsigned)(((1ULL << 32) + sz - 1) / (unsigned)sz);
    int nsb = (n_edges + SCHUNK - 1) / SCHUNK;            // stage blocks (625)

    // Workspace layout (~11.6 MB):
    unsigned short* P1b = (unsigned short*)d_ws;              // [n][64] bf16   2.56 MB
    unsigned short* P2b = P1b + (size_t)n_nodes * H1;         // [n][32] bf16   1.28 MB
    unsigned short* slots = P2b + (size_t)n_nodes * H2;       // [n][CAP]       5.12 MB
    int* cnt = (int*)(slots + ((size_t)n_nodes << CAPSH));    // [n]            80 KB
    unsigned* staged = (unsigned*)(cnt + n_nodes);            // [nsb][1024]    2.56 MB
    int* bofs = (int*)(staged + (size_t)nsb * SCHUNK);        // [9][nsb]       22.5 KB

    int g1 = nsb + (n_nodes + 31) / 32;                       // 625 + 625
    k1_kernel<<<g1, 256, 0, stream>>>(F, W1, src, dst, staged, bofs, P1b, cnt,
                                      inv_sz, n_nodes, n_edges, nsb);
    fill2_kernel<<<FILL_BPG * NG8, 256, 0, stream>>>(staged, bofs, cnt, slots, nsb);
    int bpg = (sz + 3) / 4;
    agg1gemm2_kernel<<<bpg * NG8, 256, 0, stream>>>(P1b, cnt, slots, b1, W2, P2b, n_nodes, sz);
    agg2_kernel<<<bpg * NG8, 256, 0, stream>>>(P2b, cnt, slots, b2, out, n_nodes, sz);
}

// Round 14
// 81.518 us; speedup vs baseline: 6.2724x; 1.0914x over previous
//
#include <hip/hip_runtime.h>

// GCN: out = agg(relu(agg(F)@W1 + b1)) @ W2 + b2
// Reordered (agg linear): P1 = F@W1 (bf16); A1 = b1 + agg(P1); P2 = relu(A1)@W2 (bf16);
//                         out = b2 + agg(P2)
// r13 skeleton; ONE change (bisection): gemm1 role's F loads.
//   r9/r10/r13 all had k1 ~40-48us regardless of W1-in-LDS vs W1-in-VGPR — the
//   invariant was the wave-uniform broadcast F load chain (128 sequential 16B
//   loads, in-flight depth capped by VGPRs -> ~13 serialized L3 latencies/wave;
//   PMC: wave lifetime ~30K cyc for ~3K cyc of work). Fix: stage 8 rows/wave into
//   LDS via 4 INDEPENDENT per-lane-coalesced float4 loads (one latency), then FMA
//   reads rows as LDS broadcast (same-addr, conflict-free; proven arow pattern).
// Lessons kept: no grid.sync (r7), no per-window compaction (r8), XCD-local slot
// writes (r4), ballot histogram (r10), shfl outside divergent guards (r13).

#define NF 128
#define H1 64
#define H2 32
#define CAP 128       // slot capacity/node; deg ~ Poisson(32), P(>128) ~ 1e-30; guarded
#define CAPSH 7
#define NG8 8         // node-range groups (== XCDs)
#define SCHUNK 1024   // edges per stage block
#define FILL_BPG 80   // fill2 blocks per group

__device__ __forceinline__ float blo(unsigned u){ return __uint_as_float(u << 16); }
__device__ __forceinline__ float bhi(unsigned u){ return __uint_as_float(u & 0xffff0000u); }
__device__ __forceinline__ unsigned short f2b(float f){   // fp32 -> bf16 RNE
    unsigned x = __float_as_uint(f);
    return (unsigned short)((x + 0x7fffu + ((x >> 16) & 1u)) >> 16);
}

// ---- K1: stage blocks (bid < nsb) + gemm1 blocks (bid >= nsb) ----
__launch_bounds__(256)
__global__ void k1_kernel(const float* __restrict__ F, const float* __restrict__ W1,
                          const int* __restrict__ src, const int* __restrict__ dst,
                          unsigned* __restrict__ staged, int* __restrict__ bofs,
                          unsigned short* __restrict__ P1b, int* __restrict__ cnt,
                          unsigned inv_sz, int n_nodes, int n_edges, int nsb) {
    __shared__ __align__(16) float shbuf[4][8][NF];   // 16 KB: frow (gemm) / sorted (stage)
    __shared__ int wcnt[4][NG8];
    __shared__ int wbase[4][NG8];
    __shared__ int bb0[NG8 + 1];
    const int t = threadIdx.x;
    const int bid = blockIdx.x;
    const int wid = t >> 6, lane = t & 63;

    if (bid < nsb) {
        // ---------- stage role (r13 verbatim): sort 1024-edge chunk by group ----------
        unsigned* sorted = (unsigned*)&shbuf[0][0][0];     // first 4 KB
        int e0 = bid * SCHUNK;
        int ce = min(n_edges - e0, SCHUNK);
        int i4 = e0 + t * 4;
        int dd[4], ss[4], bb[4], pp[4];
        bool val[4];
        if (i4 + 4 <= n_edges) {
            int4 d4 = *(const int4*)(dst + i4);
            int4 s4 = *(const int4*)(src + i4);
            dd[0]=d4.x; dd[1]=d4.y; dd[2]=d4.z; dd[3]=d4.w;
            ss[0]=s4.x; ss[1]=s4.y; ss[2]=s4.z; ss[3]=s4.w;
        } else {
#pragma unroll
            for (int k = 0; k < 4; ++k) {
                int e = i4 + k;
                dd[k] = (e < n_edges) ? dst[e] : -1;
                ss[k] = (e < n_edges) ? src[e] : 0;
            }
        }
        unsigned long long lt = (1ULL << lane) - 1ULL;
#pragma unroll
        for (int k = 0; k < 4; ++k) {
            val[k] = dd[k] >= 0;
            bb[k] = val[k]
                ? (int)(unsigned)(((unsigned long long)(unsigned)dd[k] * inv_sz) >> 32)
                : 0;
        }
#pragma unroll
        for (int b = 0; b < NG8; ++b) {
            int running = 0;
#pragma unroll
            for (int k = 0; k < 4; ++k) {
                unsigned long long m = __ballot(val[k] && (bb[k] == b));
                if (val[k] && (bb[k] == b)) pp[k] = running + (int)__popcll(m & lt);
                running += (int)__popcll(m);
            }
            if (lane == 0) wcnt[wid][b] = running;
        }
        __syncthreads();
        if (t < NG8) {
            int tot = 0;
#pragma unroll
            for (int w = 0; w < 4; ++w) { wbase[w][t] = tot; tot += wcnt[w][t]; }
            bb0[t] = tot;
        }
        __syncthreads();
        if (t == 0) {
            int run = 0;
#pragma unroll
            for (int b = 0; b < NG8; ++b) { int c = bb0[b]; bb0[b] = run; run += c; }
            bb0[NG8] = run;
        }
        __syncthreads();
#pragma unroll
        for (int k = 0; k < 4; ++k)
            if (val[k])
                sorted[bb0[bb[k]] + wbase[wid][bb[k]] + pp[k]] =
                    ((unsigned)dd[k] << 16) | (unsigned)ss[k];
        __syncthreads();
        for (int j = t; j < ce; j += 256) staged[(size_t)bid * SCHUNK + j] = sorted[j];
        if (t < NG8 + 1) bofs[t * nsb + bid] = bb0[t];
        return;
    }

    // ---------- gemm1 role: zero cnt; P1b = F @ W1 (F via LDS stage, W1 in VGPRs) ----
    int gb = bid - nsb;
    int zi = gb * 256 + t;
    if (zi < n_nodes) cnt[zi] = 0;
    int row0 = gb * 32 + wid * 8;
    // Stage my wave's 8 rows: 4 independent per-lane-coalesced float4 loads (all in
    // flight at once), then wave-local ds_write_b128. No block barrier needed
    // (wave-local buffer; in-order LDS ops within a wave — proven arow pattern).
    {
        const float4* F4 = (const float4*)F;              // row stride = 32 float4
        float4 tmp[4];
#pragma unroll
        for (int j = 0; j < 4; ++j) {
            int flat = j * 64 + lane;
            int r = flat >> 5, c4 = flat & 31;
            int row = row0 + r;
            int rc = min(row, n_nodes - 1);               // clamp reads; stores guarded
            tmp[j] = F4[(size_t)rc * 32 + c4];
        }
#pragma unroll
        for (int j = 0; j < 4; ++j) {
            int flat = j * 64 + lane;
            int r = flat >> 5, c4 = flat & 31;
            *(float4*)&shbuf[wid][r][c4 * 4] = tmp[j];
        }
    }
    float acc[8] = {0.f, 0.f, 0.f, 0.f, 0.f, 0.f, 0.f, 0.f};
#pragma unroll 1
    for (int cc = 0; cc < 2; ++cc) {             // two 64-k chunks (caps VGPR use)
        float wreg[64];                          // my column's 64 weights, in registers
#pragma unroll
        for (int k = 0; k < 64; ++k) wreg[k] = W1[(cc * 64 + k) * H1 + lane];
#pragma unroll
        for (int r = 0; r < 8; ++r) {
            const float4* fr = (const float4*)&shbuf[wid][r][cc * 64];
#pragma unroll
            for (int k4 = 0; k4 < 16; ++k4) {
                float4 fv = fr[k4];              // LDS broadcast read (same addr/wave)
                acc[r] += fv.x * wreg[k4 * 4 + 0] + fv.y * wreg[k4 * 4 + 1]
                        + fv.z * wreg[k4 * 4 + 2] + fv.w * wreg[k4 * 4 + 3];
            }
        }
    }
#pragma unroll
    for (int r = 0; r < 8; ++r) {
        int row = row0 + r;
        if (row < n_nodes) P1b[(size_t)row * H1 + lane] = f2b(acc[r]);
    }
}

// ---- K2: fill2 (r13 verbatim) ----
__launch_bounds__(256)
__global__ void fill2_kernel(const unsigned* __restrict__ staged, const int* __restrict__ bofs,
                             int* __restrict__ cnt, unsigned short* __restrict__ slots,
                             int nsb) {
    int g = blockIdx.x & (NG8 - 1), gi = blockIdx.x >> 3;
    for (int sb = gi; sb < nsb; sb += FILL_BPG) {
        int st = bofs[g * nsb + sb];
        int en = bofs[(g + 1) * nsb + sb];
        const unsigned* seg = staged + (size_t)sb * SCHUNK;
        for (int j = st + threadIdx.x; j < en; j += 256) {
            unsigned u = seg[j];
            int d = u >> 16;
            int p = atomicAdd(&cnt[d], 1);
            if (p < CAP) slots[(d << CAPSH) + p] = (unsigned short)(u & 0xffffu);
        }
    }
}

// ---- K3: agg1 + bias + relu + gemm2 -> P2b (r13 verbatim) ----
__launch_bounds__(256)
__global__ void agg1gemm2_kernel(const unsigned short* __restrict__ P1b,
                                 const int* __restrict__ cnt, const unsigned short* __restrict__ slots,
                                 const float* __restrict__ b1, const float* __restrict__ W2,
                                 unsigned short* __restrict__ P2b, int n_nodes, int sz) {
    __shared__ float w2s[H1 * H2];   // 8 KB
    __shared__ float arow[4][H1];    // 1 KB
    {
        const float4* w4 = (const float4*)W2;
        float4* ws4 = (float4*)w2s;
#pragma unroll
        for (int j = 0; j < 2; ++j) ws4[threadIdx.x + 256 * j] = w4[threadIdx.x + 256 * j];
    }
    __syncthreads();
    int wid = threadIdx.x >> 6, lane = threadIdx.x & 63;
    int g = blockIdx.x & (NG8 - 1), gi = blockIdx.x >> 3;
    int ni = gi * 4 + wid;
    if (ni >= sz) return;
    int node = g * sz + ni;
    if (node >= n_nodes) return;
    int deg = min(cnt[node], CAP);
    int base = node << CAPSH;
    int q = lane >> 4, c = lane & 15;
    int mys = (lane < deg) ? (int)slots[base + lane] : 0;   // one coalesced 128B load
    int dmain = min(deg, 64);
    const uint2* P1v = (const uint2*)P1b;             // row = 16 uint2 (64 bf16)
    float a0=0.f,a1=0.f,a2=0.f,a3=0.f, b0=0.f,b1v=0.f,b2v=0.f,b3=0.f;
    float c0=0.f,c1=0.f,c2=0.f,c3=0.f, d0=0.f,d1=0.f,d2=0.f,d3=0.f;
    int i = 0;
    for (; i + 16 <= dmain; i += 16) {                // full wave active: shfl safe
        int sA = __shfl(mys, i + q, 64);
        int sB = __shfl(mys, i + 4 + q, 64);
        int sC = __shfl(mys, i + 8 + q, 64);
        int sD = __shfl(mys, i + 12 + q, 64);
        uint2 uA = P1v[(sA << 4) + c];
        uint2 uB = P1v[(sB << 4) + c];
        uint2 uC = P1v[(sC << 4) + c];
        uint2 uD = P1v[(sD << 4) + c];
        a0 += blo(uA.x); a1 += bhi(uA.x); a2 += blo(uA.y); a3 += bhi(uA.y);
        b0 += blo(uB.x); b1v += bhi(uB.x); b2v += blo(uB.y); b3 += bhi(uB.y);
        c0 += blo(uC.x); c1 += bhi(uC.x); c2 += blo(uC.y); c3 += bhi(uC.y);
        d0 += blo(uD.x); d1 += bhi(uD.x); d2 += blo(uD.y); d3 += bhi(uD.y);
    }
    for (; i + 4 <= dmain; i += 4) {                  // full wave active: shfl safe
        int sA = __shfl(mys, i + q, 64);
        uint2 uA = P1v[(sA << 4) + c];
        a0 += blo(uA.x); a1 += bhi(uA.x); a2 += blo(uA.y); a3 += bhi(uA.y);
    }
    {   // partial last group: shfl HOISTED above the divergent guard
        int sA = __shfl(mys, i + q, 64);
        if (q < dmain - i) {
            uint2 uA = P1v[(sA << 4) + c];
            a0 += blo(uA.x); a1 += bhi(uA.x); a2 += blo(uA.y); a3 += bhi(uA.y);
        }
    }
    for (int j = 64 + q; j < deg; j += 4) {           // rare deg>64 tail, direct loads
        int sA = slots[base + j];
        uint2 uA = P1v[(sA << 4) + c];
        a0 += blo(uA.x); a1 += bhi(uA.x); a2 += blo(uA.y); a3 += bhi(uA.y);
    }
    a0 += b0 + c0 + d0; a1 += b1v + c1 + d1; a2 += b2v + c2 + d2; a3 += b3 + c3 + d3;
    a0 += __shfl_xor(a0, 16, 64); a0 += __shfl_xor(a0, 32, 64);
    a1 += __shfl_xor(a1, 16, 64); a1 += __shfl_xor(a1, 32, 64);
    a2 += __shfl_xor(a2, 16, 64); a2 += __shfl_xor(a2, 32, 64);
    a3 += __shfl_xor(a3, 16, 64); a3 += __shfl_xor(a3, 32, 64);
    if (q == 0) {
        float4 bb = *(const float4*)(b1 + 4 * c);
        float4 v;
        v.x = fmaxf(a0 + bb.x, 0.f);
        v.y = fmaxf(a1 + bb.y, 0.f);
        v.z = fmaxf(a2 + bb.z, 0.f);
        v.w = fmaxf(a3 + bb.w, 0.f);
        *(float4*)&arow[wid][4 * c] = v;
    }
    // wave-local LDS bounce (in-order within wave)
    int half = lane >> 5, c32 = lane & 31, kb = half * 32;
    float acc2 = 0.f;
#pragma unroll
    for (int k = 0; k < 32; ++k) acc2 += arow[wid][kb + k] * w2s[(kb + k) * H2 + c32];
    acc2 += __shfl_xor(acc2, 32, 64);
    if (lane < 32) P2b[(size_t)node * H2 + c32] = f2b(acc2);
}

// ---- K4: agg2 + bias -> out (r13 verbatim) ----
__launch_bounds__(256)
__global__ void agg2_kernel(const unsigned short* __restrict__ P2b,
                            const int* __restrict__ cnt, const unsigned short* __restrict__ slots,
                            const float* __restrict__ b2, float* __restrict__ out,
                            int n_nodes, int sz) {
    int wid = threadIdx.x >> 6, lane = threadIdx.x & 63;
    int g = blockIdx.x & (NG8 - 1), gi = blockIdx.x >> 3;
    int ni = gi * 4 + wid;
    if (ni >= sz) return;
    int node = g * sz + ni;
    if (node >= n_nodes) return;
    int deg = min(cnt[node], CAP);
    int base = node << CAPSH;
    int o = lane >> 3, c = lane & 7;
    int mys = (lane < deg) ? (int)slots[base + lane] : 0;   // one coalesced load
    int dmain = min(deg, 64);
    const uint2* P2v = (const uint2*)P2b;             // row = 8 uint2 (32 bf16)
    float a0=0.f,a1=0.f,a2=0.f,a3=0.f, b0=0.f,b1v=0.f,b2v=0.f,b3=0.f;
    float c0=0.f,c1=0.f,c2=0.f,c3=0.f, d0=0.f,d1=0.f,d2=0.f,d3=0.f;
    int i = 0;
    for (; i + 32 <= dmain; i += 32) {                // full wave active: shfl safe
        int sA = __shfl(mys, i + o, 64);
        int sB = __shfl(mys, i + 8 + o, 64);
        int sC = __shfl(mys, i + 16 + o, 64);
        int sD = __shfl(mys, i + 24 + o, 64);
        uint2 uA = P2v[(sA << 3) + c];
        uint2 uB = P2v[(sB << 3) + c];
        uint2 uC = P2v[(sC << 3) + c];
        uint2 uD = P2v[(sD << 3) + c];
        a0 += blo(uA.x); a1 += bhi(uA.x); a2 += blo(uA.y); a3 += bhi(uA.y);
        b0 += blo(uB.x); b1v += bhi(uB.x); b2v += blo(uB.y); b3 += bhi(uB.y);
        c0 += blo(uC.x); c1 += bhi(uC.x); c2 += blo(uC.y); c3 += bhi(uC.y);
        d0 += blo(uD.x); d1 += bhi(uD.x); d2 += blo(uD.y); d3 += bhi(uD.y);
    }
    for (; i + 8 <= dmain; i += 8) {                  // full wave active: shfl safe
        int sA = __shfl(mys, i + o, 64);
        uint2 uA = P2v[(sA << 3) + c];
        a0 += blo(uA.x); a1 += bhi(uA.x); a2 += blo(uA.y); a3 += bhi(uA.y);
    }
    {   // partial last group: shfl HOISTED above the divergent guard
        int sA = __shfl(mys, i + o, 64);
        if (o < dmain - i) {
            uint2 uA = P2v[(sA << 3) + c];
            a0 += blo(uA.x); a1 += bhi(uA.x); a2 += blo(uA.y); a3 += bhi(uA.y);
        }
    }
    for (int j = 64 + o; j < deg; j += 8) {           // rare deg>64 tail
        int sA = slots[base + j];
        uint2 uA = P2v[(sA << 3) + c];
        a0 += blo(uA.x); a1 += bhi(uA.x); a2 += blo(uA.y); a3 += bhi(uA.y);
    }
    a0 += b0 + c0 + d0; a1 += b1v + c1 + d1; a2 += b2v + c2 + d2; a3 += b3 + c3 + d3;
    a0 += __shfl_xor(a0, 8, 64); a0 += __shfl_xor(a0, 16, 64); a0 += __shfl_xor(a0, 32, 64);
    a1 += __shfl_xor(a1, 8, 64); a1 += __shfl_xor(a1, 16, 64); a1 += __shfl_xor(a1, 32, 64);
    a2 += __shfl_xor(a2, 8, 64); a2 += __shfl_xor(a2, 16, 64); a2 += __shfl_xor(a2, 32, 64);
    a3 += __shfl_xor(a3, 8, 64); a3 += __shfl_xor(a3, 16, 64); a3 += __shfl_xor(a3, 32, 64);
    if (o == 0) {
        float4 bb = *(const float4*)(b2 + 4 * c);
        float4 v;
        v.x = a0 + bb.x; v.y = a1 + bb.y; v.z = a2 + bb.z; v.w = a3 + bb.w;
        *(float4*)(out + (size_t)node * H2 + 4 * c) = v;
    }
}

extern "C" void kernel_launch(void* const* d_in, const int* in_sizes, int n_in,
                              void* d_out, int out_size, void* d_ws, size_t ws_size,
                              hipStream_t stream) {
    const float* F  = (const float*)d_in[0];
    const float* W1 = (const float*)d_in[1];
    const float* b1 = (const float*)d_in[2];
    const float* W2 = (const float*)d_in[3];
    const float* b2 = (const float*)d_in[4];
    const int* src  = (const int*)d_in[5];
    const int* dst  = (const int*)d_in[6];
    float* out = (float*)d_out;

    int n_nodes = in_sizes[0] / NF;                       // 20000
    int n_edges = in_sizes[5];                            // 640000
    int sz = (n_nodes + NG8 - 1) / NG8;                   // nodes per group (2500)
    unsigned inv_sz = (unsigned)(((1ULL << 32) + sz - 1) / (unsigned)sz);
    int nsb = (n_edges + SCHUNK - 1) / SCHUNK;            // stage blocks (625)

    // Workspace layout (~11.6 MB):
    unsigned short* P1b = (unsigned short*)d_ws;              // [n][64] bf16   2.56 MB
    unsigned short* P2b = P1b + (size_t)n_nodes * H1;         // [n][32] bf16   1.28 MB
    unsigned short* slots = P2b + (size_t)n_nodes * H2;       // [n][CAP]       5.12 MB
    int* cnt = (int*)(slots + ((size_t)n_nodes << CAPSH));    // [n]            80 KB
    unsigned* staged = (unsigned*)(cnt + n_nodes);            // [nsb][1024]    2.56 MB
    int* bofs = (int*)(staged + (size_t)nsb * SCHUNK);        // [9][nsb]       22.5 KB

    int g1 = nsb + (n_nodes + 31) / 32;                       // 625 + 625
    k1_kernel<<<g1, 256, 0, stream>>>(F, W1, src, dst, staged, bofs, P1b, cnt,
                                      inv_sz, n_nodes, n_edges, nsb);
    fill2_kernel<<<FILL_BPG * NG8, 256, 0, stream>>>(staged, bofs, cnt, slots, nsb);
    int bpg = (sz + 3) / 4;
    agg1gemm2_kernel<<<bpg * NG8, 256, 0, stream>>>(P1b, cnt, slots, b1, W2, P2b, n_nodes, sz);
    agg2_kernel<<<bpg * NG8, 256, 0, stream>>>(P2b, cnt, slots, b2, out, n_nodes, sz);
}